// Round 1
// baseline (1980.549 us; speedup 1.0000x reference)
//
#include <hip/hip_runtime.h>
#include <stdint.h>

// VCSMC: N=16 taxa, K=128 particles, S=512 sites, A=4, D=64, 15 rounds.
// Strategy: bit-exact threefry PRNG (partitionable variant) + order-faithful
// float32 arithmetic mirroring XLA-CPU reduction/matmul order, so all
// argmax-based control flow (resampling, proposals, best-particle) matches
// the JAX reference exactly.

#define NN 16
#define KK 128
#define SS 512
#define NR 15
#define PARTITIONABLE 1   // modern JAX default (jax_threefry_partitionable=True)
#define TINYF 1.17549435e-38f

// ---------------- threefry2x32 (JAX-exact) ----------------
__host__ __device__ __forceinline__ void tf2x32(uint32_t k0, uint32_t k1,
                                                uint32_t c0, uint32_t c1,
                                                uint32_t* o0, uint32_t* o1) {
  uint32_t ks2 = k0 ^ k1 ^ 0x1BD11BDAu;
  uint32_t x0 = c0 + k0, x1 = c1 + k1;
  uint32_t ks[3] = {k0, k1, ks2};
  const uint32_t RA[4] = {13u, 15u, 26u, 6u};
  const uint32_t RB[4] = {17u, 29u, 16u, 24u};
#pragma unroll
  for (int i = 0; i < 5; ++i) {
#pragma unroll
    for (int j = 0; j < 4; ++j) {
      uint32_t r = (i & 1) ? RB[j] : RA[j];
      x0 += x1;
      x1 = (x1 << r) | (x1 >> (32u - r));
      x1 ^= x0;
    }
    x0 += ks[(i + 1) % 3];
    x1 += ks[(i + 2) % 3] + (uint32_t)(i + 1);
  }
  *o0 = x0; *o1 = x1;
}

// random bits for flat element i of a draw of `total` 32-bit words
__device__ __forceinline__ uint32_t rbits32(uint32_t ka, uint32_t kb,
                                            uint32_t i, uint32_t total) {
#if PARTITIONABLE
  uint32_t o0, o1;
  tf2x32(ka, kb, 0u, i, &o0, &o1);
  return o0 ^ o1;
#else
  uint32_t half = total >> 1;
  uint32_t o0, o1;
  if (i < half) { tf2x32(ka, kb, i, i + half, &o0, &o1); return o0; }
  tf2x32(ka, kb, i - half, i, &o0, &o1);
  return o1;
#endif
}

__device__ __forceinline__ float bits_unif(uint32_t b) {
  return __uint_as_float((b >> 9) | 0x3f800000u) - 1.0f;  // [0,1)
}

// XLA CPU fast-tanh (math_ops.cc EmitFastTanh, with_fma=false) replicated.
__device__ __forceinline__ float xla_tanh(float x) {
  float ax = fabsf(x);
  float xc = fminf(fmaxf(x, -7.90531110763549805f), 7.90531110763549805f);
  float x2 = __fmul_rn(xc, xc);
  float num = -2.76076847742355e-16f;
  num = __fadd_rn(__fmul_rn(x2, num), 2.00018790482477e-13f);
  num = __fadd_rn(__fmul_rn(x2, num), -8.60467152213735e-11f);
  num = __fadd_rn(__fmul_rn(x2, num), 5.12229709037114e-08f);
  num = __fadd_rn(__fmul_rn(x2, num), 1.48572235717979e-05f);
  num = __fadd_rn(__fmul_rn(x2, num), 6.37261928875436e-04f);
  num = __fadd_rn(__fmul_rn(x2, num), 4.89352455891786e-03f);
  num = __fmul_rn(xc, num);
  float den = 1.19825839466702e-06f;
  den = __fadd_rn(__fmul_rn(x2, den), 1.18534705686654e-04f);
  den = __fadd_rn(__fmul_rn(x2, den), 2.26843463243900e-03f);
  den = __fadd_rn(__fmul_rn(x2, den), 4.89352518554385e-03f);
  float r = __fdiv_rn(num, den);
  return (ax < 0.0004f) ? x : r;
}

__device__ __forceinline__ float fin_or0(float v) {
  return (v > -INFINITY && v < INFINITY) ? v : 0.0f;
}

// ---------------- setup kernels ----------------
__global__ void k_init_misc(float* logw, float* logpi0, int* lc0, float* logdf) {
  int t = threadIdx.x;
  if (t < KK) { logw[t] = 0.0f; logpi0[t] = 0.0f; }
  for (int i = t; i < KK * 16; i += blockDim.x) lc0[i] = 1;
  if (t == 0) {
    double v[33];
    v[0] = 0.0; v[1] = 0.0;
    for (int i = 2; i <= 32; ++i) v[i] = v[i - 2] + log((double)i);
    for (int i = 0; i < 33; ++i) logdf[i] = (float)v[i];
  }
}

// site_logits[s][a] = sum_c W_pos[s][c]*W_site[c][a]   (siteC == W_pos exactly)
__global__ void k_sitelog(const float* Wpos, const float* Wsite, float* sitelog) {
  int id = blockIdx.x * blockDim.x + threadIdx.x;
  if (id >= SS * 4) return;
  int s = id >> 2, a = id & 3;
  float acc = 0.0f;
  for (int c = 0; c < 16; ++c) acc = fmaf(Wpos[s * 16 + c], Wsite[c * 4 + a], acc);
  sitelog[id] = acc;
}

__global__ void k_emb0(const float* data, const float* Wenc, float* emb0) {
  int n = blockIdx.x, d = threadIdx.x;
  float acc = 0.0f;
  for (int i = 0; i < 2048; ++i) acc = fmaf(data[n * 2048 + i], Wenc[i * 64 + d], acc);
  float v = xla_tanh(acc);
  for (int k = 0; k < KK; ++k) emb0[(k * 16 + n) * 64 + d] = v;
}

__global__ void k_ew0(const float* emb0, const float* Wstat, float* ew0) {
  int t = threadIdx.x;
  if (t >= 64) return;
  int n = t >> 2, a = t & 3;
  float acc = 0.0f;
  for (int d = 0; d < 64; ++d) acc = fmaf(emb0[n * 64 + d], Wstat[d * 4 + a], acc);
  ew0[n * 4 + a] = acc;
}

__global__ void k_leaffel(const float* datab, float* fel0) {
  int id = blockIdx.x * blockDim.x + threadIdx.x;
  if (id >= NN * SS * 4) return;
  float v = logf(datab[id]);
  int n = id / 2048, rest = id % 2048;
  for (int k = 0; k < KK; ++k) fel0[(k * 16 + n) * 2048 + rest] = v;
}

__global__ void k_leafterm(const float* fel0, const float* ew0,
                           const float* sitelog, float* st0) {
  int id = blockIdx.x * blockDim.x + threadIdx.x;
  if (id >= NN * SS) return;
  int n = id >> 9, s = id & 511;
  float lg[4], ex[4], stat[4];
  for (int a = 0; a < 4; ++a) lg[a] = __fadd_rn(ew0[n * 4 + a], sitelog[s * 4 + a]);
  float m = lg[0];
  for (int a = 1; a < 4; ++a) m = fmaxf(m, lg[a]);
  float ssum = 0.0f;
  for (int a = 0; a < 4; ++a) { ex[a] = expf(__fsub_rn(lg[a], m)); ssum = __fadd_rn(ssum, ex[a]); }
  for (int a = 0; a < 4; ++a) stat[a] = __fdiv_rn(ex[a], ssum);
  float q[4], am = -INFINITY;
  for (int a = 0; a < 4; ++a) {
    q[a] = __fadd_rn(fel0[n * 2048 + s * 4 + a], logf(stat[a]));
    am = fmaxf(am, q[a]);
  }
  am = fin_or0(am);
  float se = 0.0f;
  for (int a = 0; a < 4; ++a) se = __fadd_rn(se, expf(__fsub_rn(q[a], am)));
  float v = __fadd_rn(logf(se), am);
  for (int k = 0; k < KK; ++k) st0[(k * 16 + n) * 512 + s] = v;
}

// ---------------- per-round kernels ----------------
// categorical resampling: idxK[i] = first argmax_j (gumbel[i,j] + logw[j])
__global__ void k_resample(uint32_t ka, uint32_t kb, const float* logw, int* idxK) {
  int i = blockIdx.x, j = threadIdx.x;
  uint32_t bits = rbits32(ka, kb, (uint32_t)(i * KK + j), KK * KK);
  float f = bits_unif(bits);
  float u = fmaxf(TINYF, __fadd_rn(f, TINYF));  // uniform(minval=tiny): f*(1-tiny)+tiny, (1-tiny)==1
  float gv = -logf(-logf(u));
  float v = __fadd_rn(gv, logw[j]);
  __shared__ float smax[2];
  __shared__ int sidx[2];
  float m = v;
  for (int d = 32; d > 0; d >>= 1) m = fmaxf(m, __shfl_xor(m, d, 64));
  int w = j >> 6;
  if ((j & 63) == 0) smax[w] = m;
  __syncthreads();
  float gm = fmaxf(smax[0], smax[1]);
  int cand = (v == gm) ? j : 9999;   // exact max; first index attaining it
  for (int d = 32; d > 0; d >>= 1) { int o = __shfl_xor(cand, d, 64); cand = (o < cand) ? o : cand; }
  if ((j & 63) == 0) sidx[w] = cand;
  __syncthreads();
  if (j == 0) idxK[i] = (sidx[0] < sidx[1]) ? sidx[0] : sidx[1];
}

__global__ void k_prop(uint32_t k2a, uint32_t k2b, uint32_t k3a, uint32_t k3b,
                       uint32_t k4a, uint32_t k4b, int t,
                       int* idx1, int* idx2, float* b1, float* b2, float* lvp) {
  int i = threadIdx.x;
  if (i >= KK) return;
  // randint(k2, (K,), 0, npairs): bits shape (2,128) flat
  uint32_t h = rbits32(k2a, k2b, (uint32_t)i, 256u);
  uint32_t l = rbits32(k2a, k2b, (uint32_t)(128 + i), 256u);
  uint32_t span = (uint32_t)(t * (t - 1) / 2);
  uint32_t mult = 65536u % span;
  mult = (mult * mult) % span;
  uint32_t off = ((h % span) * mult + (l % span)) % span;
  int p = (int)off;
  int a1 = 0, rem = p, rl = t - 1;
  while (rem >= rl) { rem -= rl; ++a1; --rl; }
  idx1[i] = a1;
  idx2[i] = a1 + 1 + rem;
  // exponential draws: -log1p(-uniform)
  uint32_t bb = rbits32(k3a, k3b, (uint32_t)i, 128u);
  float f1 = bits_unif(bb);
  float e1 = -log1pf(-f1);
  bb = rbits32(k4a, k4b, (uint32_t)i, 128u);
  float f2 = bits_unif(bb);
  float e2 = -log1pf(-f2);
  b1[i] = e1; b2[i] = e2;
  float lnp = logf((float)span);
  // (-log(npairs) + (0 - b1)) + (0 - b2)
  lvp[i] = __fadd_rn(__fadd_rn(-lnp, -e1), -e2);
}

// gather (resample) + remove2 + append-new-slot bookkeeping (big arrays via float4)
__global__ void k_gather(const float4* felS, float4* felD, const float4* stS, float4* stD,
                         const float4* embS, float4* embD, const int* lcS, int* lcD,
                         const int* m1S, int* m1D, const int* m2S, int* m2D,
                         const float* br1S, float* br1D, const float* br2S, float* br2D,
                         const int* idxK, const int* idx1, const int* idx2,
                         const float* b1, const float* b2, int t, int r) {
  int tn2 = t - 2;
  int tid = blockIdx.x * blockDim.x + threadIdx.x;
  int nth = gridDim.x * blockDim.x;
  int totF = KK * tn2 * 512;
  for (int w = tid; w < totF; w += nth) {
    int k = w / (tn2 * 512), rr = w % (tn2 * 512);
    int pos = rr / 512, off = rr % 512;
    int a = idxK[k], i1 = idx1[k], i2 = idx2[k];
    int src = pos + (pos >= i1) + (pos >= (i2 - 1));
    felD[(k * 16 + pos) * 512 + off] = felS[(a * 16 + src) * 512 + off];
  }
  int totS = KK * tn2 * 128;
  for (int w = tid; w < totS; w += nth) {
    int k = w / (tn2 * 128), rr = w % (tn2 * 128);
    int pos = rr / 128, off = rr % 128;
    int a = idxK[k], i1 = idx1[k], i2 = idx2[k];
    int src = pos + (pos >= i1) + (pos >= (i2 - 1));
    stD[(k * 16 + pos) * 128 + off] = stS[(a * 16 + src) * 128 + off];
  }
  int totE = KK * tn2 * 16;
  for (int w = tid; w < totE; w += nth) {
    int k = w / (tn2 * 16), rr = w % (tn2 * 16);
    int pos = rr / 16, off = rr % 16;
    int a = idxK[k], i1 = idx1[k], i2 = idx2[k];
    int src = pos + (pos >= i1) + (pos >= (i2 - 1));
    embD[(k * 16 + pos) * 16 + off] = embS[(a * 16 + src) * 16 + off];
  }
  for (int k = tid; k < KK; k += nth) {
    int a = idxK[k], i1 = idx1[k], i2 = idx2[k];
    for (int pos = 0; pos < tn2; ++pos) {
      int src = pos + (pos >= i1) + (pos >= (i2 - 1));
      lcD[k * 16 + pos] = lcS[a * 16 + src];
    }
    lcD[k * 16 + tn2] = lcS[a * 16 + i1] + lcS[a * 16 + i2];
    for (int j = 0; j < r; ++j) {
      m1D[k * 15 + j] = m1S[a * 15 + j];
      m2D[k * 15 + j] = m2S[a * 15 + j];
      br1D[k * 15 + j] = br1S[a * 15 + j];
      br2D[k * 15 + j] = br2S[a * 15 + j];
    }
    m1D[k * 15 + r] = i1;
    m2D[k * 15 + r] = i2;
    br1D[k * 15 + r] = b1[k];
    br2D[k * 15 + r] = b2[k];
  }
}

// new_emb = tanh(concat(e1,e2) @ W_merge); ew = new_emb @ W_stat; e = exp(-b)
__global__ void k_newemb(const float* embS, float* embD, const float* Wmerge,
                         const float* Wstat, const int* idxK, const int* idx1,
                         const int* idx2, const float* b1, const float* b2,
                         float* ew, float* e1K, float* e2K, int t) {
  int k = blockIdx.x, d = threadIdx.x;
  __shared__ float cat[128];
  __shared__ float ne[64];
  int a = idxK[k];
  cat[d] = embS[(a * 16 + idx1[k]) * 64 + d];
  cat[64 + d] = embS[(a * 16 + idx2[k]) * 64 + d];
  __syncthreads();
  float acc = 0.0f;
  for (int c = 0; c < 128; ++c) acc = fmaf(cat[c], Wmerge[c * 64 + d], acc);
  float v = xla_tanh(acc);
  ne[d] = v;
  embD[(k * 16 + (t - 2)) * 64 + d] = v;
  __syncthreads();
  if (d < 4) {
    float s = 0.0f;
    for (int c = 0; c < 64; ++c) s = fmaf(ne[c], Wstat[c * 4 + d], s);
    ew[k * 4 + d] = s;
  } else if (d == 4) {
    e1K[k] = expf(-b1[k]);
  } else if (d == 5) {
    e2K[k] = expf(-b2[k]);
  }
}

// Felsenstein step at the new node + cached site-term for log_lik
__global__ void k_newfel(const float* felS, float* felD, float* stD,
                         const float* ew, const float* e1K, const float* e2K,
                         const float* sitelog, const int* idxK, const int* idx1,
                         const int* idx2, int t) {
  int id = blockIdx.x * blockDim.x + threadIdx.x;
  if (id >= KK * SS) return;
  int k = id >> 9, s = id & 511;
  float lg[4], ex[4], stat[4];
  for (int a = 0; a < 4; ++a) lg[a] = __fadd_rn(ew[k * 4 + a], sitelog[s * 4 + a]);
  float m = lg[0];
  for (int a = 1; a < 4; ++a) m = fmaxf(m, lg[a]);
  float ssum = 0.0f;
  for (int a = 0; a < 4; ++a) { ex[a] = expf(__fsub_rn(lg[a], m)); ssum = __fadd_rn(ssum, ex[a]); }
  for (int a = 0; a < 4; ++a) stat[a] = __fdiv_rn(ex[a], ssum);
  int ac = idxK[k];
  const float* f1 = felS + (ac * 16 + idx1[k]) * 2048 + s * 4;
  const float* f2 = felS + (ac * 16 + idx2[k]) * 2048 + s * 4;
  float e1 = e1K[k], e2 = e2K[k];
  float om1 = __fsub_rn(1.0f, e1), om2 = __fsub_rn(1.0f, e2);
  float nf[4];
  for (int a = 0; a < 4; ++a) {
    float q[4], am = -INFINITY;
    for (int b = 0; b < 4; ++b) {
      float P = __fadd_rn((a == b) ? e1 : 0.0f, __fmul_rn(om1, stat[b]));
      float lp = logf(__fadd_rn(P, 1e-30f));
      q[b] = __fadd_rn(lp, f1[b]);
      am = fmaxf(am, q[b]);
    }
    am = fin_or0(am);
    float se = 0.0f;
    for (int b = 0; b < 4; ++b) se = __fadd_rn(se, expf(__fsub_rn(q[b], am)));
    float h1 = __fadd_rn(logf(se), am);
    float q2[4], am2 = -INFINITY;
    for (int b = 0; b < 4; ++b) {
      float P = __fadd_rn((a == b) ? e2 : 0.0f, __fmul_rn(om2, stat[b]));
      float lp = logf(__fadd_rn(P, 1e-30f));
      q2[b] = __fadd_rn(lp, f2[b]);
      am2 = fmaxf(am2, q2[b]);
    }
    am2 = fin_or0(am2);
    float se2 = 0.0f;
    for (int b = 0; b < 4; ++b) se2 = __fadd_rn(se2, expf(__fsub_rn(q2[b], am2)));
    float h2 = __fadd_rn(logf(se2), am2);
    nf[a] = __fadd_rn(h1, h2);
  }
  float* fd = felD + (k * 16 + (t - 2)) * 2048 + s * 4;
  for (int a = 0; a < 4; ++a) fd[a] = nf[a];
  float q3[4], am3 = -INFINITY;
  for (int a = 0; a < 4; ++a) {
    q3[a] = __fadd_rn(nf[a], logf(stat[a]));
    am3 = fmaxf(am3, q3[a]);
  }
  am3 = fin_or0(am3);
  float se3 = 0.0f;
  for (int a = 0; a < 4; ++a) se3 = __fadd_rn(se3, expf(__fsub_rn(q3[a], am3)));
  stD[(k * 16 + (t - 2)) * 512 + s] = __fadd_rn(logf(se3), am3);
}

// weights: sequential (node-major, site-minor) sums to match XLA reduce order
__global__ void k_weights(const float* stD, const int* lcD, const float* logdf,
                          const float* b1h, const float* b2h, const float* logpiS,
                          float* logpiD, const int* idxK, const float* lvp,
                          float* logw, float* logws_r, float* loglik, int t, int r) {
  int k = threadIdx.x;
  if (k >= KK) return;
  int tn = t - 1;
  const float* st = stD + k * 16 * 512;
  float ll = 0.0f;
  for (int pos = 0; pos < tn; ++pos) {
    const float* row = st + pos * 512;
    for (int s = 0; s < 512; ++s) ll = __fadd_rn(ll, row[s]);
  }
  float lt = 0.0f;
  for (int pos = 0; pos < tn; ++pos) {
    int idx = 2 * lcD[k * 16 + pos] - 3;
    if (idx < 0) idx = 0;
    lt = __fadd_rn(lt, logdf[idx]);
  }
  lt = -lt;
  float s1 = 0.0f, s2 = 0.0f;
  for (int j = 0; j <= r; ++j) {
    s1 = __fadd_rn(s1, -b1h[k * 15 + j]);
    s2 = __fadd_rn(s2, -b2h[k * 15 + j]);
  }
  float lb = __fadd_rn(s1, s2);
  float lpi = __fadd_rn(__fadd_rn(ll, lt), lb);
  float prev = logpiS[idxK[k]];
  float lw = __fsub_rn(__fadd_rn(__fsub_rn(lpi, prev), 0.0f), lvp[k]);
  logpiD[k] = lpi;
  logw[k] = lw;
  logws_r[k] = lw;
  loglik[k] = ll;
}

__global__ void k_final(const float* logws, const float* loglik,
                        const int* m1D, const int* m2D,
                        const float* br1D, const float* br2D, float* out) {
  int k = threadIdx.x;
  if (k < KK) out[1 + k] = loglik[k];
  if (k == 0) {
    float c = logf(128.0f);
    float z = 0.0f;
    for (int r = 0; r < NR; ++r) {
      const float* row = logws + r * KK;
      float am = -INFINITY;
      for (int j = 0; j < KK; ++j) am = fmaxf(am, __fsub_rn(row[j], c));
      am = fin_or0(am);
      float se = 0.0f;
      for (int j = 0; j < KK; ++j) se = __fadd_rn(se, expf(__fsub_rn(__fsub_rn(row[j], c), am)));
      z = __fadd_rn(z, __fadd_rn(logf(se), am));
    }
    out[0] = z;
    float best = -INFINITY;
    int bi = 0;
    for (int j = 0; j < KK; ++j) {
      if (loglik[j] > best) { best = loglik[j]; bi = j; }
    }
    for (int j = 0; j < NR; ++j) {
      out[129 + j] = (float)m1D[bi * 15 + j];
      out[144 + j] = (float)m2D[bi * 15 + j];
      out[159 + j] = br1D[bi * 15 + j];
      out[174 + j] = br2D[bi * 15 + j];
    }
  }
}

// ---------------- host: key schedule + orchestration ----------------
static void split5_host(uint32_t* key0, uint32_t* key1, uint32_t out[8]) {
#if PARTITIONABLE
  uint32_t nk0, nk1, o0, o1;
  tf2x32(*key0, *key1, 0u, 0u, &nk0, &nk1);
  for (int j = 1; j < 5; ++j) {
    tf2x32(*key0, *key1, 0u, (uint32_t)j, &o0, &o1);
    out[2 * (j - 1)] = o0;
    out[2 * (j - 1) + 1] = o1;
  }
  *key0 = nk0; *key1 = nk1;
#else
  uint32_t a0[5], a1[5];
  for (int i = 0; i < 5; ++i) tf2x32(*key0, *key1, (uint32_t)i, (uint32_t)(i + 5), &a0[i], &a1[i]);
  uint32_t flat[10] = {a0[0], a0[1], a0[2], a0[3], a0[4], a1[0], a1[1], a1[2], a1[3], a1[4]};
  *key0 = flat[0]; *key1 = flat[1];
  for (int j = 0; j < 8; ++j) out[j] = flat[2 + j];
#endif
}

extern "C" void kernel_launch(void* const* d_in, const int* in_sizes, int n_in,
                              void* d_out, int out_size, void* d_ws, size_t ws_size,
                              hipStream_t stream) {
  const float* data = (const float*)d_in[0];
  const float* datab = (const float*)d_in[1];
  // d_in[2] = site_positions (identity; siteC == W_pos bit-exactly)
  const float* Wenc = (const float*)d_in[3];
  const float* Wmerge = (const float*)d_in[4];
  const float* Wstat = (const float*)d_in[5];
  const float* Wpos = (const float*)d_in[6];
  const float* Wsite = (const float*)d_in[7];
  float* out = (float*)d_out;

  char* base = (char*)d_ws;
  size_t off = 0;
  auto alloc = [&](size_t bytes) -> void* {
    void* p = base + off;
    off += (bytes + 255) & ~(size_t)255;
    return p;
  };
  float* fel[2]; float* st[2]; float* emb[2]; int* lc[2];
  int* m1[2]; int* m2[2]; float* br1[2]; float* br2[2]; float* logpi[2];
  for (int b = 0; b < 2; ++b) fel[b] = (float*)alloc((size_t)KK * 16 * SS * 4 * 4);
  for (int b = 0; b < 2; ++b) st[b] = (float*)alloc((size_t)KK * 16 * SS * 4);
  for (int b = 0; b < 2; ++b) emb[b] = (float*)alloc((size_t)KK * 16 * 64 * 4);
  for (int b = 0; b < 2; ++b) lc[b] = (int*)alloc((size_t)KK * 16 * 4);
  for (int b = 0; b < 2; ++b) m1[b] = (int*)alloc((size_t)KK * 15 * 4);
  for (int b = 0; b < 2; ++b) m2[b] = (int*)alloc((size_t)KK * 15 * 4);
  for (int b = 0; b < 2; ++b) br1[b] = (float*)alloc((size_t)KK * 15 * 4);
  for (int b = 0; b < 2; ++b) br2[b] = (float*)alloc((size_t)KK * 15 * 4);
  for (int b = 0; b < 2; ++b) logpi[b] = (float*)alloc((size_t)KK * 4);
  float* logw = (float*)alloc(KK * 4);
  float* logws = (float*)alloc(NR * KK * 4);
  float* loglik = (float*)alloc(KK * 4);
  int* idxK = (int*)alloc(KK * 4);
  int* idx1 = (int*)alloc(KK * 4);
  int* idx2 = (int*)alloc(KK * 4);
  float* b1 = (float*)alloc(KK * 4);
  float* b2 = (float*)alloc(KK * 4);
  float* lvp = (float*)alloc(KK * 4);
  float* ew = (float*)alloc(KK * 4 * 4);
  float* e1K = (float*)alloc(KK * 4);
  float* e2K = (float*)alloc(KK * 4);
  float* sitelog = (float*)alloc(SS * 4 * 4);
  float* logdf = (float*)alloc(33 * 4);
  float* ew0 = (float*)alloc(NN * 4 * 4);
  (void)ws_size; (void)in_sizes; (void)n_in; (void)out_size;

  // setup
  k_init_misc<<<1, 128, 0, stream>>>(logw, logpi[0], lc[0], logdf);
  k_sitelog<<<8, 256, 0, stream>>>(Wpos, Wsite, sitelog);
  k_emb0<<<NN, 64, 0, stream>>>(data, Wenc, emb[0]);
  k_ew0<<<1, 64, 0, stream>>>(emb[0], Wstat, ew0);
  k_leaffel<<<128, 256, 0, stream>>>(datab, fel[0]);
  k_leafterm<<<32, 256, 0, stream>>>(fel[0], ew0, sitelog, st[0]);

  uint32_t key0 = 0u, key1 = 42u;  // jax.random.key(42)
  for (int r = 0; r < NR; ++r) {
    uint32_t ks[8];
    split5_host(&key0, &key1, ks);  // key, k1, k2, k3, k4
    int t = NN - r;
    int cur = r & 1, nxt = cur ^ 1;
    k_resample<<<KK, 128, 0, stream>>>(ks[0], ks[1], logw, idxK);
    k_prop<<<1, 128, 0, stream>>>(ks[2], ks[3], ks[4], ks[5], ks[6], ks[7], t,
                                  idx1, idx2, b1, b2, lvp);
    k_gather<<<512, 256, 0, stream>>>((const float4*)fel[cur], (float4*)fel[nxt],
                                      (const float4*)st[cur], (float4*)st[nxt],
                                      (const float4*)emb[cur], (float4*)emb[nxt],
                                      lc[cur], lc[nxt], m1[cur], m1[nxt], m2[cur], m2[nxt],
                                      br1[cur], br1[nxt], br2[cur], br2[nxt],
                                      idxK, idx1, idx2, b1, b2, t, r);
    k_newemb<<<KK, 64, 0, stream>>>(emb[cur], emb[nxt], Wmerge, Wstat, idxK, idx1,
                                    idx2, b1, b2, ew, e1K, e2K, t);
    k_newfel<<<KK * SS / 256, 256, 0, stream>>>(fel[cur], fel[nxt], st[nxt], ew, e1K,
                                                e2K, sitelog, idxK, idx1, idx2, t);
    k_weights<<<1, 128, 0, stream>>>(st[nxt], lc[nxt], logdf, br1[nxt], br2[nxt],
                                     logpi[cur], logpi[nxt], idxK, lvp, logw,
                                     logws + r * KK, loglik, t, r);
  }
  // after r=14: nxt == 1
  k_final<<<1, 128, 0, stream>>>(logws, loglik, m1[1], m2[1], br1[1], br2[1], out);
}

// Round 2
// 687.976 us; speedup vs baseline: 2.8788x; 2.8788x over previous
//
#include <hip/hip_runtime.h>
#include <stdint.h>

// VCSMC: N=16 taxa, K=128 particles, S=512 sites, A=4, D=64, 15 rounds.
// Bit-exact threefry (partitionable) + order-faithful float32 so all argmax
// decisions match the JAX reference. Round 2: keep all decision-feeding
// arithmetic bit-identical; restructure for latency:
//  - k_weights: 1 wave/particle, LDS-staged rows, lane-0 exact serial fold
//  - k_final: parallel (exact max/argmax; parallel exp-sum only hits out[0])
//  - fused resample+prop and gather+newemb kernels (4 launches/round)

#define NN 16
#define KK 128
#define SS 512
#define NR 15
#define PARTITIONABLE 1
#define TINYF 1.17549435e-38f

// ---------------- threefry2x32 (JAX-exact) ----------------
__host__ __device__ __forceinline__ void tf2x32(uint32_t k0, uint32_t k1,
                                                uint32_t c0, uint32_t c1,
                                                uint32_t* o0, uint32_t* o1) {
  uint32_t ks2 = k0 ^ k1 ^ 0x1BD11BDAu;
  uint32_t x0 = c0 + k0, x1 = c1 + k1;
  uint32_t ks[3] = {k0, k1, ks2};
  const uint32_t RA[4] = {13u, 15u, 26u, 6u};
  const uint32_t RB[4] = {17u, 29u, 16u, 24u};
#pragma unroll
  for (int i = 0; i < 5; ++i) {
#pragma unroll
    for (int j = 0; j < 4; ++j) {
      uint32_t r = (i & 1) ? RB[j] : RA[j];
      x0 += x1;
      x1 = (x1 << r) | (x1 >> (32u - r));
      x1 ^= x0;
    }
    x0 += ks[(i + 1) % 3];
    x1 += ks[(i + 2) % 3] + (uint32_t)(i + 1);
  }
  *o0 = x0; *o1 = x1;
}

__device__ __forceinline__ uint32_t rbits32(uint32_t ka, uint32_t kb,
                                            uint32_t i, uint32_t total) {
#if PARTITIONABLE
  uint32_t o0, o1;
  tf2x32(ka, kb, 0u, i, &o0, &o1);
  return o0 ^ o1;
#else
  uint32_t half = total >> 1;
  uint32_t o0, o1;
  if (i < half) { tf2x32(ka, kb, i, i + half, &o0, &o1); return o0; }
  tf2x32(ka, kb, i - half, i, &o0, &o1);
  return o1;
#endif
}

__device__ __forceinline__ float bits_unif(uint32_t b) {
  return __uint_as_float((b >> 9) | 0x3f800000u) - 1.0f;  // [0,1)
}

// XLA CPU fast-tanh (with_fma=false) replicated.
__device__ __forceinline__ float xla_tanh(float x) {
  float ax = fabsf(x);
  float xc = fminf(fmaxf(x, -7.90531110763549805f), 7.90531110763549805f);
  float x2 = __fmul_rn(xc, xc);
  float num = -2.76076847742355e-16f;
  num = __fadd_rn(__fmul_rn(x2, num), 2.00018790482477e-13f);
  num = __fadd_rn(__fmul_rn(x2, num), -8.60467152213735e-11f);
  num = __fadd_rn(__fmul_rn(x2, num), 5.12229709037114e-08f);
  num = __fadd_rn(__fmul_rn(x2, num), 1.48572235717979e-05f);
  num = __fadd_rn(__fmul_rn(x2, num), 6.37261928875436e-04f);
  num = __fadd_rn(__fmul_rn(x2, num), 4.89352455891786e-03f);
  num = __fmul_rn(xc, num);
  float den = 1.19825839466702e-06f;
  den = __fadd_rn(__fmul_rn(x2, den), 1.18534705686654e-04f);
  den = __fadd_rn(__fmul_rn(x2, den), 2.26843463243900e-03f);
  den = __fadd_rn(__fmul_rn(x2, den), 4.89352518554385e-03f);
  float r = __fdiv_rn(num, den);
  return (ax < 0.0004f) ? x : r;
}

__device__ __forceinline__ float fin_or0(float v) {
  return (v > -INFINITY && v < INFINITY) ? v : 0.0f;
}

// ---------------- setup kernels ----------------
__global__ void k_init_misc(float* logw, float* logpi0, int* lc0, float* logdf) {
  int t = threadIdx.x;
  if (t < KK) { logw[t] = 0.0f; logpi0[t] = 0.0f; }
  for (int i = t; i < KK * 16; i += blockDim.x) lc0[i] = 1;
  if (t == 0) {
    double v[33];
    v[0] = 0.0; v[1] = 0.0;
    for (int i = 2; i <= 32; ++i) v[i] = v[i - 2] + log((double)i);
    for (int i = 0; i < 33; ++i) logdf[i] = (float)v[i];
  }
}

__global__ void k_sitelog(const float* Wpos, const float* Wsite, float* sitelog) {
  int id = blockIdx.x * blockDim.x + threadIdx.x;
  if (id >= SS * 4) return;
  int s = id >> 2, a = id & 3;
  float acc = 0.0f;
  for (int c = 0; c < 16; ++c) acc = fmaf(Wpos[s * 16 + c], Wsite[c * 4 + a], acc);
  sitelog[id] = acc;
}

__global__ void k_emb0(const float* data, const float* Wenc, float* emb0) {
  int n = blockIdx.x, d = threadIdx.x;
  float acc = 0.0f;
  for (int i = 0; i < 2048; ++i) acc = fmaf(data[n * 2048 + i], Wenc[i * 64 + d], acc);
  float v = xla_tanh(acc);
  for (int k = 0; k < KK; ++k) emb0[(k * 16 + n) * 64 + d] = v;
}

__global__ void k_ew0(const float* emb0, const float* Wstat, float* ew0) {
  int t = threadIdx.x;
  if (t >= 64) return;
  int n = t >> 2, a = t & 3;
  float acc = 0.0f;
  for (int d = 0; d < 64; ++d) acc = fmaf(emb0[n * 64 + d], Wstat[d * 4 + a], acc);
  ew0[n * 4 + a] = acc;
}

__global__ void k_leaffel(const float* datab, float* fel0) {
  int id = blockIdx.x * blockDim.x + threadIdx.x;
  if (id >= NN * SS * 4) return;
  float v = logf(datab[id]);
  int n = id / 2048, rest = id % 2048;
  for (int k = 0; k < KK; ++k) fel0[(k * 16 + n) * 2048 + rest] = v;
}

__global__ void k_leafterm(const float* fel0, const float* ew0,
                           const float* sitelog, float* st0) {
  int id = blockIdx.x * blockDim.x + threadIdx.x;
  if (id >= NN * SS) return;
  int n = id >> 9, s = id & 511;
  float lg[4], ex[4], stat[4];
  for (int a = 0; a < 4; ++a) lg[a] = __fadd_rn(ew0[n * 4 + a], sitelog[s * 4 + a]);
  float m = lg[0];
  for (int a = 1; a < 4; ++a) m = fmaxf(m, lg[a]);
  float ssum = 0.0f;
  for (int a = 0; a < 4; ++a) { ex[a] = expf(__fsub_rn(lg[a], m)); ssum = __fadd_rn(ssum, ex[a]); }
  for (int a = 0; a < 4; ++a) stat[a] = __fdiv_rn(ex[a], ssum);
  float q[4], am = -INFINITY;
  for (int a = 0; a < 4; ++a) {
    q[a] = __fadd_rn(fel0[n * 2048 + s * 4 + a], logf(stat[a]));
    am = fmaxf(am, q[a]);
  }
  am = fin_or0(am);
  float se = 0.0f;
  for (int a = 0; a < 4; ++a) se = __fadd_rn(se, expf(__fsub_rn(q[a], am)));
  float v = __fadd_rn(logf(se), am);
  for (int k = 0; k < KK; ++k) st0[(k * 16 + n) * 512 + s] = v;
}

// ---------------- per-round kernels ----------------
// blocks 0..127: categorical draw i; block 128: pair/branch proposal
__global__ void k_resample_prop(uint32_t ka, uint32_t kb,
                                uint32_t k2a, uint32_t k2b, uint32_t k3a, uint32_t k3b,
                                uint32_t k4a, uint32_t k4b, int t,
                                const float* logw, int* idxK,
                                int* idx1, int* idx2, float* b1, float* b2, float* lvp) {
  if (blockIdx.x < KK) {
    int i = blockIdx.x, j = threadIdx.x;
    uint32_t bits = rbits32(ka, kb, (uint32_t)(i * KK + j), KK * KK);
    float f = bits_unif(bits);
    float u = fmaxf(TINYF, __fadd_rn(f, TINYF));
    float gv = -logf(-logf(u));
    float v = __fadd_rn(gv, logw[j]);
    __shared__ float smax[2];
    __shared__ int sidx[2];
    float m = v;
    for (int d = 32; d > 0; d >>= 1) m = fmaxf(m, __shfl_xor(m, d, 64));
    int w = j >> 6;
    if ((j & 63) == 0) smax[w] = m;
    __syncthreads();
    float gm = fmaxf(smax[0], smax[1]);
    int cand = (v == gm) ? j : 9999;
    for (int d = 32; d > 0; d >>= 1) { int o = __shfl_xor(cand, d, 64); cand = (o < cand) ? o : cand; }
    if ((j & 63) == 0) sidx[w] = cand;
    __syncthreads();
    if (j == 0) idxK[i] = (sidx[0] < sidx[1]) ? sidx[0] : sidx[1];
    return;
  }
  // proposal block
  int i = threadIdx.x;
  if (i >= KK) return;
  uint32_t h = rbits32(k2a, k2b, (uint32_t)i, 256u);
  uint32_t l = rbits32(k2a, k2b, (uint32_t)(128 + i), 256u);
  uint32_t span = (uint32_t)(t * (t - 1) / 2);
  uint32_t mult = 65536u % span;
  mult = (mult * mult) % span;
  uint32_t off = ((h % span) * mult + (l % span)) % span;
  int p = (int)off;
  int a1 = 0, rem = p, rl = t - 1;
  while (rem >= rl) { rem -= rl; ++a1; --rl; }
  idx1[i] = a1;
  idx2[i] = a1 + 1 + rem;
  uint32_t bb = rbits32(k3a, k3b, (uint32_t)i, 128u);
  float f1 = bits_unif(bb);
  float e1 = -log1pf(-f1);
  bb = rbits32(k4a, k4b, (uint32_t)i, 128u);
  float f2 = bits_unif(bb);
  float e2 = -log1pf(-f2);
  b1[i] = e1; b2[i] = e2;
  float lnp = logf((float)span);
  lvp[i] = __fadd_rn(__fadd_rn(-lnp, -e1), -e2);
}

// blocks 0..511: gather (resample + remove2) of big arrays
// blocks 512..639: new_emb = tanh(cat @ W_merge), ew, exp(-b) for particle b-512
__global__ void k_gather_newemb(const float4* felS, float4* felD, const float4* stS, float4* stD,
                                const float4* embS, float4* embD, const int* lcS, int* lcD,
                                const int* m1S, int* m1D, const int* m2S, int* m2D,
                                const float* br1S, float* br1D, const float* br2S, float* br2D,
                                const int* idxK, const int* idx1, const int* idx2,
                                const float* b1, const float* b2,
                                const float* embSf, float* embDf, const float* Wmerge,
                                const float* Wstat, float* ew, float* e1K, float* e2K,
                                int t, int r) {
  int tn2 = t - 2;
  if (blockIdx.x >= 512) {
    int k = blockIdx.x - 512;
    int d = threadIdx.x;
    __shared__ float cat[128];
    __shared__ float ne[64];
    int a = idxK[k];
    if (d < 64) {
      cat[d] = embSf[(a * 16 + idx1[k]) * 64 + d];
      cat[64 + d] = embSf[(a * 16 + idx2[k]) * 64 + d];
    }
    __syncthreads();
    if (d < 64) {
      float acc = 0.0f;
      for (int c = 0; c < 128; ++c) acc = fmaf(cat[c], Wmerge[c * 64 + d], acc);
      float v = xla_tanh(acc);
      ne[d] = v;
      embDf[(k * 16 + (t - 2)) * 64 + d] = v;
    }
    __syncthreads();
    if (d < 4) {
      float s = 0.0f;
      for (int c = 0; c < 64; ++c) s = fmaf(ne[c], Wstat[c * 4 + d], s);
      ew[k * 4 + d] = s;
    } else if (d == 4) {
      e1K[k] = expf(-b1[k]);
    } else if (d == 5) {
      e2K[k] = expf(-b2[k]);
    }
    return;
  }
  int tid = blockIdx.x * 256 + threadIdx.x;
  const int nth = 512 * 256;
  int totF = KK * tn2 * 512;
  for (int w = tid; w < totF; w += nth) {
    int k = w / (tn2 * 512), rr = w % (tn2 * 512);
    int pos = rr / 512, off = rr % 512;
    int a = idxK[k], i1 = idx1[k], i2 = idx2[k];
    int src = pos + (pos >= i1) + (pos >= (i2 - 1));
    felD[(k * 16 + pos) * 512 + off] = felS[(a * 16 + src) * 512 + off];
  }
  int totS = KK * tn2 * 128;
  for (int w = tid; w < totS; w += nth) {
    int k = w / (tn2 * 128), rr = w % (tn2 * 128);
    int pos = rr / 128, off = rr % 128;
    int a = idxK[k], i1 = idx1[k], i2 = idx2[k];
    int src = pos + (pos >= i1) + (pos >= (i2 - 1));
    stD[(k * 16 + pos) * 128 + off] = stS[(a * 16 + src) * 128 + off];
  }
  int totE = KK * tn2 * 16;
  for (int w = tid; w < totE; w += nth) {
    int k = w / (tn2 * 16), rr = w % (tn2 * 16);
    int pos = rr / 16, off = rr % 16;
    int a = idxK[k], i1 = idx1[k], i2 = idx2[k];
    int src = pos + (pos >= i1) + (pos >= (i2 - 1));
    embD[(k * 16 + pos) * 16 + off] = embS[(a * 16 + src) * 16 + off];
  }
  for (int k = tid; k < KK; k += nth) {
    int a = idxK[k], i1 = idx1[k], i2 = idx2[k];
    for (int pos = 0; pos < tn2; ++pos) {
      int src = pos + (pos >= i1) + (pos >= (i2 - 1));
      lcD[k * 16 + pos] = lcS[a * 16 + src];
    }
    lcD[k * 16 + tn2] = lcS[a * 16 + i1] + lcS[a * 16 + i2];
    for (int j = 0; j < r; ++j) {
      m1D[k * 15 + j] = m1S[a * 15 + j];
      m2D[k * 15 + j] = m2S[a * 15 + j];
      br1D[k * 15 + j] = br1S[a * 15 + j];
      br2D[k * 15 + j] = br2S[a * 15 + j];
    }
    m1D[k * 15 + r] = i1;
    m2D[k * 15 + r] = i2;
    br1D[k * 15 + r] = b1[k];
    br2D[k * 15 + r] = b2[k];
  }
}

// Felsenstein step at the new node + cached site-term for log_lik
__global__ void k_newfel(const float* felS, float* felD, float* stD,
                         const float* ew, const float* e1K, const float* e2K,
                         const float* sitelog, const int* idxK, const int* idx1,
                         const int* idx2, int t) {
  int id = blockIdx.x * blockDim.x + threadIdx.x;
  if (id >= KK * SS) return;
  int k = id >> 9, s = id & 511;
  float lg[4], ex[4], stat[4];
  for (int a = 0; a < 4; ++a) lg[a] = __fadd_rn(ew[k * 4 + a], sitelog[s * 4 + a]);
  float m = lg[0];
  for (int a = 1; a < 4; ++a) m = fmaxf(m, lg[a]);
  float ssum = 0.0f;
  for (int a = 0; a < 4; ++a) { ex[a] = expf(__fsub_rn(lg[a], m)); ssum = __fadd_rn(ssum, ex[a]); }
  for (int a = 0; a < 4; ++a) stat[a] = __fdiv_rn(ex[a], ssum);
  int ac = idxK[k];
  const float* f1 = felS + (ac * 16 + idx1[k]) * 2048 + s * 4;
  const float* f2 = felS + (ac * 16 + idx2[k]) * 2048 + s * 4;
  float e1 = e1K[k], e2 = e2K[k];
  float om1 = __fsub_rn(1.0f, e1), om2 = __fsub_rn(1.0f, e2);
  float nf[4];
  for (int a = 0; a < 4; ++a) {
    float q[4], am = -INFINITY;
    for (int b = 0; b < 4; ++b) {
      float P = __fadd_rn((a == b) ? e1 : 0.0f, __fmul_rn(om1, stat[b]));
      float lp = logf(__fadd_rn(P, 1e-30f));
      q[b] = __fadd_rn(lp, f1[b]);
      am = fmaxf(am, q[b]);
    }
    am = fin_or0(am);
    float se = 0.0f;
    for (int b = 0; b < 4; ++b) se = __fadd_rn(se, expf(__fsub_rn(q[b], am)));
    float h1 = __fadd_rn(logf(se), am);
    float q2[4], am2 = -INFINITY;
    for (int b = 0; b < 4; ++b) {
      float P = __fadd_rn((a == b) ? e2 : 0.0f, __fmul_rn(om2, stat[b]));
      float lp = logf(__fadd_rn(P, 1e-30f));
      q2[b] = __fadd_rn(lp, f2[b]);
      am2 = fmaxf(am2, q2[b]);
    }
    am2 = fin_or0(am2);
    float se2 = 0.0f;
    for (int b = 0; b < 4; ++b) se2 = __fadd_rn(se2, expf(__fsub_rn(q2[b], am2)));
    float h2 = __fadd_rn(logf(se2), am2);
    nf[a] = __fadd_rn(h1, h2);
  }
  float* fd = felD + (k * 16 + (t - 2)) * 2048 + s * 4;
  for (int a = 0; a < 4; ++a) fd[a] = nf[a];
  float q3[4], am3 = -INFINITY;
  for (int a = 0; a < 4; ++a) {
    q3[a] = __fadd_rn(nf[a], logf(stat[a]));
    am3 = fmaxf(am3, q3[a]);
  }
  am3 = fin_or0(am3);
  float se3 = 0.0f;
  for (int a = 0; a < 4; ++a) se3 = __fadd_rn(se3, expf(__fsub_rn(q3[a], am3)));
  stD[(k * 16 + (t - 2)) * 512 + s] = __fadd_rn(logf(se3), am3);
}

// weights: one wave per particle. All 64 lanes stage each 512-float row into
// LDS (hiding global latency under the fold); lane 0 performs the EXACT
// sequential left-fold (bit-identical to the reference order).
__global__ void k_weights(const float* stD, const int* lcD, const float* logdf,
                          const float* b1h, const float* b2h, const float* logpiS,
                          float* logpiD, const int* idxK, const float* lvp,
                          float* logw, float* logws_r, float* loglik, int t, int r) {
  int k = blockIdx.x;
  int lane = threadIdx.x;
  int tn = t - 1;
  __shared__ float buf[2][512];
  const float4* st4 = (const float4*)(stD + k * 16 * 512);  // 128 float4 per row
  // prologue: stage row 0
  {
    float4 va = st4[lane], vb = st4[64 + lane];
    ((float4*)buf[0])[lane] = va;
    ((float4*)buf[0])[64 + lane] = vb;
  }
  __syncthreads();
  float ll = 0.0f;
  for (int pos = 0; pos < tn; ++pos) {
    int cur = pos & 1;
    // issue next-row loads (row pos+1 <= 15 always allocated; last is unused)
    int np = pos + 1;
    float4 na = st4[np * 128 + lane];
    float4 nb = st4[np * 128 + 64 + lane];
    // exact serial fold of current row by lane 0
    if (lane == 0) {
      const float4* b4 = (const float4*)buf[cur];
      for (int q = 0; q < 128; ++q) {
        float4 v = b4[q];
        ll = __fadd_rn(ll, v.x);
        ll = __fadd_rn(ll, v.y);
        ll = __fadd_rn(ll, v.z);
        ll = __fadd_rn(ll, v.w);
      }
    }
    // stage next row into the other buffer (in-order after the fold)
    ((float4*)buf[cur ^ 1])[lane] = na;
    ((float4*)buf[cur ^ 1])[64 + lane] = nb;
    __syncthreads();
  }
  if (lane == 0) {
    float lt = 0.0f;
    for (int pos = 0; pos < tn; ++pos) {
      int idx = 2 * lcD[k * 16 + pos] - 3;
      if (idx < 0) idx = 0;
      lt = __fadd_rn(lt, logdf[idx]);
    }
    lt = -lt;
    float s1 = 0.0f, s2 = 0.0f;
    for (int j = 0; j <= r; ++j) {
      s1 = __fadd_rn(s1, -b1h[k * 15 + j]);
      s2 = __fadd_rn(s2, -b2h[k * 15 + j]);
    }
    float lb = __fadd_rn(s1, s2);
    float lpi = __fadd_rn(__fadd_rn(ll, lt), lb);
    float prev = logpiS[idxK[k]];
    float lw = __fsub_rn(__fadd_rn(__fsub_rn(lpi, prev), 0.0f), lvp[k]);
    logpiD[k] = lpi;
    logw[k] = lw;
    logws_r[k] = lw;
    loglik[k] = ll;
  }
}

// final: parallel. Exact max / first-argmax (fmaxf is associative-exact);
// parallel exp-sum only affects out[0] (large threshold).
__global__ void k_final(const float* logws, const float* loglik,
                        const int* m1D, const int* m2D,
                        const float* br1D, const float* br2D, float* out) {
  int j = threadIdx.x;  // 128 threads
  out[1 + j] = loglik[j];
  __shared__ float sm[2];
  __shared__ float ssum[2];
  __shared__ int si[2];
  float c = logf(128.0f);
  float z = 0.0f;
  for (int r = 0; r < NR; ++r) {
    float v = __fsub_rn(logws[r * KK + j], c);
    float m = v;
    for (int d = 32; d > 0; d >>= 1) m = fmaxf(m, __shfl_xor(m, d, 64));
    if ((j & 63) == 0) sm[j >> 6] = m;
    __syncthreads();
    float gm = fin_or0(fmaxf(sm[0], sm[1]));
    float e = expf(__fsub_rn(v, gm));
    for (int d = 32; d > 0; d >>= 1) e = __fadd_rn(e, __shfl_xor(e, d, 64));
    if ((j & 63) == 0) ssum[j >> 6] = e;
    __syncthreads();
    if (j == 0) z = __fadd_rn(z, __fadd_rn(logf(__fadd_rn(ssum[0], ssum[1])), gm));
    __syncthreads();
  }
  if (j == 0) out[0] = z;
  // best particle: exact first-index-of-max
  float lv = loglik[j];
  float m2 = lv;
  for (int d = 32; d > 0; d >>= 1) m2 = fmaxf(m2, __shfl_xor(m2, d, 64));
  if ((j & 63) == 0) sm[j >> 6] = m2;
  __syncthreads();
  float gm2 = fmaxf(sm[0], sm[1]);
  int cand = (lv == gm2) ? j : 9999;
  for (int d = 32; d > 0; d >>= 1) { int o = __shfl_xor(cand, d, 64); cand = (o < cand) ? o : cand; }
  if ((j & 63) == 0) si[j >> 6] = cand;
  __syncthreads();
  int bi = (si[0] < si[1]) ? si[0] : si[1];
  if (j < NR) {
    out[129 + j] = (float)m1D[bi * 15 + j];
    out[144 + j] = (float)m2D[bi * 15 + j];
    out[159 + j] = br1D[bi * 15 + j];
    out[174 + j] = br2D[bi * 15 + j];
  }
}

// ---------------- host: key schedule + orchestration ----------------
static void split5_host(uint32_t* key0, uint32_t* key1, uint32_t out[8]) {
#if PARTITIONABLE
  uint32_t nk0, nk1, o0, o1;
  tf2x32(*key0, *key1, 0u, 0u, &nk0, &nk1);
  for (int j = 1; j < 5; ++j) {
    tf2x32(*key0, *key1, 0u, (uint32_t)j, &o0, &o1);
    out[2 * (j - 1)] = o0;
    out[2 * (j - 1) + 1] = o1;
  }
  *key0 = nk0; *key1 = nk1;
#else
  uint32_t a0[5], a1[5];
  for (int i = 0; i < 5; ++i) tf2x32(*key0, *key1, (uint32_t)i, (uint32_t)(i + 5), &a0[i], &a1[i]);
  uint32_t flat[10] = {a0[0], a0[1], a0[2], a0[3], a0[4], a1[0], a1[1], a1[2], a1[3], a1[4]};
  *key0 = flat[0]; *key1 = flat[1];
  for (int j = 0; j < 8; ++j) out[j] = flat[2 + j];
#endif
}

extern "C" void kernel_launch(void* const* d_in, const int* in_sizes, int n_in,
                              void* d_out, int out_size, void* d_ws, size_t ws_size,
                              hipStream_t stream) {
  const float* data = (const float*)d_in[0];
  const float* datab = (const float*)d_in[1];
  const float* Wenc = (const float*)d_in[3];
  const float* Wmerge = (const float*)d_in[4];
  const float* Wstat = (const float*)d_in[5];
  const float* Wpos = (const float*)d_in[6];
  const float* Wsite = (const float*)d_in[7];
  float* out = (float*)d_out;

  char* base = (char*)d_ws;
  size_t off = 0;
  auto alloc = [&](size_t bytes) -> void* {
    void* p = base + off;
    off += (bytes + 255) & ~(size_t)255;
    return p;
  };
  float* fel[2]; float* st[2]; float* emb[2]; int* lc[2];
  int* m1[2]; int* m2[2]; float* br1[2]; float* br2[2]; float* logpi[2];
  for (int b = 0; b < 2; ++b) fel[b] = (float*)alloc((size_t)KK * 16 * SS * 4 * 4);
  for (int b = 0; b < 2; ++b) st[b] = (float*)alloc((size_t)KK * 16 * SS * 4);
  for (int b = 0; b < 2; ++b) emb[b] = (float*)alloc((size_t)KK * 16 * 64 * 4);
  for (int b = 0; b < 2; ++b) lc[b] = (int*)alloc((size_t)KK * 16 * 4);
  for (int b = 0; b < 2; ++b) m1[b] = (int*)alloc((size_t)KK * 15 * 4);
  for (int b = 0; b < 2; ++b) m2[b] = (int*)alloc((size_t)KK * 15 * 4);
  for (int b = 0; b < 2; ++b) br1[b] = (float*)alloc((size_t)KK * 15 * 4);
  for (int b = 0; b < 2; ++b) br2[b] = (float*)alloc((size_t)KK * 15 * 4);
  for (int b = 0; b < 2; ++b) logpi[b] = (float*)alloc((size_t)KK * 4);
  float* logw = (float*)alloc(KK * 4);
  float* logws = (float*)alloc(NR * KK * 4);
  float* loglik = (float*)alloc(KK * 4);
  int* idxK = (int*)alloc(KK * 4);
  int* idx1 = (int*)alloc(KK * 4);
  int* idx2 = (int*)alloc(KK * 4);
  float* b1 = (float*)alloc(KK * 4);
  float* b2 = (float*)alloc(KK * 4);
  float* lvp = (float*)alloc(KK * 4);
  float* ew = (float*)alloc(KK * 4 * 4);
  float* e1K = (float*)alloc(KK * 4);
  float* e2K = (float*)alloc(KK * 4);
  float* sitelog = (float*)alloc(SS * 4 * 4);
  float* logdf = (float*)alloc(33 * 4);
  float* ew0 = (float*)alloc(NN * 4 * 4);
  (void)ws_size; (void)in_sizes; (void)n_in; (void)out_size;

  // setup
  k_init_misc<<<1, 128, 0, stream>>>(logw, logpi[0], lc[0], logdf);
  k_sitelog<<<8, 256, 0, stream>>>(Wpos, Wsite, sitelog);
  k_emb0<<<NN, 64, 0, stream>>>(data, Wenc, emb[0]);
  k_ew0<<<1, 64, 0, stream>>>(emb[0], Wstat, ew0);
  k_leaffel<<<128, 256, 0, stream>>>(datab, fel[0]);
  k_leafterm<<<32, 256, 0, stream>>>(fel[0], ew0, sitelog, st[0]);

  uint32_t key0 = 0u, key1 = 42u;  // jax.random.key(42)
  for (int r = 0; r < NR; ++r) {
    uint32_t ks[8];
    split5_host(&key0, &key1, ks);  // key, k1, k2, k3, k4
    int t = NN - r;
    int cur = r & 1, nxt = cur ^ 1;
    k_resample_prop<<<KK + 1, 128, 0, stream>>>(ks[0], ks[1], ks[2], ks[3], ks[4],
                                                ks[5], ks[6], ks[7], t, logw, idxK,
                                                idx1, idx2, b1, b2, lvp);
    k_gather_newemb<<<640, 256, 0, stream>>>((const float4*)fel[cur], (float4*)fel[nxt],
                                             (const float4*)st[cur], (float4*)st[nxt],
                                             (const float4*)emb[cur], (float4*)emb[nxt],
                                             lc[cur], lc[nxt], m1[cur], m1[nxt], m2[cur], m2[nxt],
                                             br1[cur], br1[nxt], br2[cur], br2[nxt],
                                             idxK, idx1, idx2, b1, b2,
                                             emb[cur], emb[nxt], Wmerge, Wstat, ew, e1K, e2K,
                                             t, r);
    k_newfel<<<KK * SS / 256, 256, 0, stream>>>(fel[cur], fel[nxt], st[nxt], ew, e1K,
                                                e2K, sitelog, idxK, idx1, idx2, t);
    k_weights<<<KK, 64, 0, stream>>>(st[nxt], lc[nxt], logdf, br1[nxt], br2[nxt],
                                     logpi[cur], logpi[nxt], idxK, lvp, logw,
                                     logws + r * KK, loglik, t, r);
  }
  // after r=14: nxt == 1
  k_final<<<1, 128, 0, stream>>>(logws, loglik, m1[1], m2[1], br1[1], br2[1], out);
}

// Round 3
// 650.826 us; speedup vs baseline: 3.0431x; 1.0571x over previous
//
#include <hip/hip_runtime.h>
#include <stdint.h>

// VCSMC: N=16 taxa, K=128 particles, S=512 sites, A=4, D=64, 15 rounds.
// Bit-exact threefry (partitionable) + order-faithful float32 so all argmax
// decisions match the JAX reference. Round 3: copy-on-write row pools
// (fel/st/emb/lc are immutable rows; particles hold index lists) eliminate
// all big gathers; k_emb0 restructured for latency; newfel+weights fused.
// All decision-feeding arithmetic is bit-identical to the passing round-2.

#define NN 16
#define KK 128
#define SS 512
#define NR 15
#define PARTITIONABLE 1
#define TINYF 1.17549435e-38f
#define NROWS (NN + NR * KK)   // 1936 pool rows

// ---------------- threefry2x32 (JAX-exact) ----------------
__host__ __device__ __forceinline__ void tf2x32(uint32_t k0, uint32_t k1,
                                                uint32_t c0, uint32_t c1,
                                                uint32_t* o0, uint32_t* o1) {
  uint32_t ks2 = k0 ^ k1 ^ 0x1BD11BDAu;
  uint32_t x0 = c0 + k0, x1 = c1 + k1;
  uint32_t ks[3] = {k0, k1, ks2};
  const uint32_t RA[4] = {13u, 15u, 26u, 6u};
  const uint32_t RB[4] = {17u, 29u, 16u, 24u};
#pragma unroll
  for (int i = 0; i < 5; ++i) {
#pragma unroll
    for (int j = 0; j < 4; ++j) {
      uint32_t r = (i & 1) ? RB[j] : RA[j];
      x0 += x1;
      x1 = (x1 << r) | (x1 >> (32u - r));
      x1 ^= x0;
    }
    x0 += ks[(i + 1) % 3];
    x1 += ks[(i + 2) % 3] + (uint32_t)(i + 1);
  }
  *o0 = x0; *o1 = x1;
}

__device__ __forceinline__ uint32_t rbits32(uint32_t ka, uint32_t kb,
                                            uint32_t i, uint32_t total) {
#if PARTITIONABLE
  uint32_t o0, o1;
  tf2x32(ka, kb, 0u, i, &o0, &o1);
  return o0 ^ o1;
#else
  uint32_t half = total >> 1;
  uint32_t o0, o1;
  if (i < half) { tf2x32(ka, kb, i, i + half, &o0, &o1); return o0; }
  tf2x32(ka, kb, i - half, i, &o0, &o1);
  return o1;
#endif
}

__device__ __forceinline__ float bits_unif(uint32_t b) {
  return __uint_as_float((b >> 9) | 0x3f800000u) - 1.0f;  // [0,1)
}

// XLA CPU fast-tanh (with_fma=false) replicated.
__device__ __forceinline__ float xla_tanh(float x) {
  float ax = fabsf(x);
  float xc = fminf(fmaxf(x, -7.90531110763549805f), 7.90531110763549805f);
  float x2 = __fmul_rn(xc, xc);
  float num = -2.76076847742355e-16f;
  num = __fadd_rn(__fmul_rn(x2, num), 2.00018790482477e-13f);
  num = __fadd_rn(__fmul_rn(x2, num), -8.60467152213735e-11f);
  num = __fadd_rn(__fmul_rn(x2, num), 5.12229709037114e-08f);
  num = __fadd_rn(__fmul_rn(x2, num), 1.48572235717979e-05f);
  num = __fadd_rn(__fmul_rn(x2, num), 6.37261928875436e-04f);
  num = __fadd_rn(__fmul_rn(x2, num), 4.89352455891786e-03f);
  num = __fmul_rn(xc, num);
  float den = 1.19825839466702e-06f;
  den = __fadd_rn(__fmul_rn(x2, den), 1.18534705686654e-04f);
  den = __fadd_rn(__fmul_rn(x2, den), 2.26843463243900e-03f);
  den = __fadd_rn(__fmul_rn(x2, den), 4.89352518554385e-03f);
  float r = __fdiv_rn(num, den);
  return (ax < 0.0004f) ? x : r;
}

__device__ __forceinline__ float fin_or0(float v) {
  return (v > -INFINITY && v < INFINITY) ? v : 0.0f;
}

// ---------------- setup kernels ----------------
__global__ void k_init(float* logw, float* logpi0, int* lc_pool, int* ilist0,
                       float* logdf) {
  int t = threadIdx.x;  // 128
  logw[t] = 0.0f;
  logpi0[t] = 0.0f;
  if (t < NN) lc_pool[t] = 1;
  for (int n = 0; n < NN; ++n) ilist0[t * 16 + n] = n;
  if (t == 0) {
    double v[33];
    v[0] = 0.0; v[1] = 0.0;
    for (int i = 2; i <= 32; ++i) v[i] = v[i - 2] + log((double)i);
    for (int i = 0; i < 33; ++i) logdf[i] = (float)v[i];
  }
}

__global__ void k_sitelog(const float* Wpos, const float* Wsite, float* sitelog) {
  int id = blockIdx.x * blockDim.x + threadIdx.x;
  if (id >= SS * 4) return;
  int s = id >> 2, a = id & 3;
  float acc = 0.0f;
  for (int c = 0; c < 16; ++c) acc = fmaf(Wpos[s * 16 + c], Wsite[c * 4 + a], acc);
  sitelog[id] = acc;
}

// seq_encoder: emb = tanh(data_row @ Wenc), identical fmaf fold order per
// (n,d) as the passing version, but fed from LDS with waves 1-3 prefetching.
// Fused: ew0 = emb @ Wstat (same fold order as the old k_ew0).
__global__ void k_emb0(const float* data, const float* Wenc, const float* Wstat,
                       float* emb_pool, float* ew0) {
  int n = blockIdx.x, tid = threadIdx.x;
  int lane = tid & 63, wid = tid >> 6;
  __shared__ float drow[2048];
  __shared__ float wch[2][64 * 64];
  __shared__ float ne[64];
  const float4* d4 = (const float4*)(data + n * 2048);
  float4* dr4 = (float4*)drow;
  dr4[tid] = d4[tid];
  dr4[256 + tid] = d4[256 + tid];
  const float4* w4 = (const float4*)Wenc;
  {
    float4* dst = (float4*)wch[0];
    for (int q = tid; q < 1024; q += 256) dst[q] = w4[q];
  }
  __syncthreads();
  float acc = 0.0f;
  for (int c = 0; c < 32; ++c) {
    if (wid > 0 && c < 31) {
      float4* dst = (float4*)wch[(c + 1) & 1];
      const float4* src = w4 + (c + 1) * 1024;
      for (int q = tid - 64; q < 1024; q += 192) dst[q] = src[q];
    }
    if (wid == 0) {
      const float* wc = wch[c & 1];
      const float* dr = drow + c * 64;
      for (int i = 0; i < 64; ++i) acc = fmaf(dr[i], wc[i * 64 + lane], acc);
    }
    __syncthreads();
  }
  if (wid == 0) {
    float v = xla_tanh(acc);
    ne[lane] = v;
    emb_pool[n * 64 + lane] = v;
  }
  __syncthreads();
  if (tid < 4) {
    float s = 0.0f;
    for (int c = 0; c < 64; ++c) s = fmaf(ne[c], Wstat[c * 4 + tid], s);
    ew0[n * 4 + tid] = s;
  }
}

__global__ void k_leaffel(const float* datab, float* fel_pool) {
  int id = blockIdx.x * blockDim.x + threadIdx.x;
  if (id >= NN * SS * 4) return;
  fel_pool[id] = logf(datab[id]);
}

__global__ void k_leafterm(const float* fel_pool, const float* ew0,
                           const float* sitelog, float* st_pool) {
  int id = blockIdx.x * blockDim.x + threadIdx.x;
  if (id >= NN * SS) return;
  int n = id >> 9, s = id & 511;
  float lg[4], ex[4], stat[4];
  for (int a = 0; a < 4; ++a) lg[a] = __fadd_rn(ew0[n * 4 + a], sitelog[s * 4 + a]);
  float m = lg[0];
  for (int a = 1; a < 4; ++a) m = fmaxf(m, lg[a]);
  float ssum = 0.0f;
  for (int a = 0; a < 4; ++a) { ex[a] = expf(__fsub_rn(lg[a], m)); ssum = __fadd_rn(ssum, ex[a]); }
  for (int a = 0; a < 4; ++a) stat[a] = __fdiv_rn(ex[a], ssum);
  float q[4], am = -INFINITY;
  for (int a = 0; a < 4; ++a) {
    q[a] = __fadd_rn(fel_pool[n * 2048 + s * 4 + a], logf(stat[a]));
    am = fmaxf(am, q[a]);
  }
  am = fin_or0(am);
  float se = 0.0f;
  for (int a = 0; a < 4; ++a) se = __fadd_rn(se, expf(__fsub_rn(q[a], am)));
  st_pool[n * 512 + s] = __fadd_rn(logf(se), am);
}

// ---------------- per-round kernels ----------------
// blocks 0..127: categorical draw i; block 128: pair/branch proposal
__global__ void k_resample_prop(uint32_t ka, uint32_t kb,
                                uint32_t k2a, uint32_t k2b, uint32_t k3a, uint32_t k3b,
                                uint32_t k4a, uint32_t k4b, int t,
                                const float* logw, int* idxK,
                                int* idx1, int* idx2, float* b1, float* b2, float* lvp) {
  if (blockIdx.x < KK) {
    int i = blockIdx.x, j = threadIdx.x;
    uint32_t bits = rbits32(ka, kb, (uint32_t)(i * KK + j), KK * KK);
    float f = bits_unif(bits);
    float u = fmaxf(TINYF, __fadd_rn(f, TINYF));
    float gv = -logf(-logf(u));
    float v = __fadd_rn(gv, logw[j]);
    __shared__ float smax[2];
    __shared__ int sidx[2];
    float m = v;
    for (int d = 32; d > 0; d >>= 1) m = fmaxf(m, __shfl_xor(m, d, 64));
    int w = j >> 6;
    if ((j & 63) == 0) smax[w] = m;
    __syncthreads();
    float gm = fmaxf(smax[0], smax[1]);
    int cand = (v == gm) ? j : 9999;
    for (int d = 32; d > 0; d >>= 1) { int o = __shfl_xor(cand, d, 64); cand = (o < cand) ? o : cand; }
    if ((j & 63) == 0) sidx[w] = cand;
    __syncthreads();
    if (j == 0) idxK[i] = (sidx[0] < sidx[1]) ? sidx[0] : sidx[1];
    return;
  }
  int i = threadIdx.x;
  if (i >= KK) return;
  uint32_t h = rbits32(k2a, k2b, (uint32_t)i, 256u);
  uint32_t l = rbits32(k2a, k2b, (uint32_t)(128 + i), 256u);
  uint32_t span = (uint32_t)(t * (t - 1) / 2);
  uint32_t mult = 65536u % span;
  mult = (mult * mult) % span;
  uint32_t off = ((h % span) * mult + (l % span)) % span;
  int p = (int)off;
  int a1 = 0, rem = p, rl = t - 1;
  while (rem >= rl) { rem -= rl; ++a1; --rl; }
  idx1[i] = a1;
  idx2[i] = a1 + 1 + rem;
  uint32_t bb = rbits32(k3a, k3b, (uint32_t)i, 128u);
  float f1 = bits_unif(bb);
  float e1 = -log1pf(-f1);
  bb = rbits32(k4a, k4b, (uint32_t)i, 128u);
  float f2 = bits_unif(bb);
  float e2 = -log1pf(-f2);
  b1[i] = e1; b2[i] = e2;
  float lnp = logf((float)span);
  lvp[i] = __fadd_rn(__fadd_rn(-lnp, -e1), -e2);
}

// blocks 0..127: new_emb for particle k (same fmaf/tanh order as before)
// block 128: index-list + history bookkeeping (copy-on-write pools)
__global__ void k_newemb_bk(float* emb_pool, const float* Wmerge, const float* Wstat,
                            const int* ilistC, int* ilistN,
                            const int* idxK, const int* idx1, const int* idx2,
                            const float* b1, const float* b2,
                            const int* m1C, int* m1N, const int* m2C, int* m2N,
                            const float* br1C, float* br1N,
                            const float* br2C, float* br2N,
                            int* lc_pool, int* pr1, int* pr2,
                            float* ew, float* e1K, float* e2K, int t, int r) {
  int newbase = NN + r * KK;
  if (blockIdx.x < KK) {
    int k = blockIdx.x, d = threadIdx.x;  // 64
    int a = idxK[k];
    int p1 = ilistC[a * 16 + idx1[k]];
    int p2 = ilistC[a * 16 + idx2[k]];
    __shared__ float cat[128];
    __shared__ float ne[64];
    cat[d] = emb_pool[p1 * 64 + d];
    cat[64 + d] = emb_pool[p2 * 64 + d];
    __syncthreads();
    float acc = 0.0f;
    for (int c = 0; c < 128; ++c) acc = fmaf(cat[c], Wmerge[c * 64 + d], acc);
    float v = xla_tanh(acc);
    ne[d] = v;
    emb_pool[(newbase + k) * 64 + d] = v;
    __syncthreads();
    if (d < 4) {
      float s = 0.0f;
      for (int c = 0; c < 64; ++c) s = fmaf(ne[c], Wstat[c * 4 + d], s);
      ew[k * 4 + d] = s;
    } else if (d == 4) {
      e1K[k] = expf(-b1[k]);
    } else if (d == 5) {
      e2K[k] = expf(-b2[k]);
    }
    return;
  }
  for (int k = threadIdx.x; k < KK; k += 64) {
    int a = idxK[k], i1 = idx1[k], i2 = idx2[k];
    int p1 = ilistC[a * 16 + i1];
    int p2 = ilistC[a * 16 + i2];
    pr1[k] = p1; pr2[k] = p2;
    int tn2 = t - 2;
    for (int pos = 0; pos < tn2; ++pos) {
      int src = pos + (pos >= i1) + (pos >= (i2 - 1));
      ilistN[k * 16 + pos] = ilistC[a * 16 + src];
    }
    int nr = newbase + k;
    ilistN[k * 16 + tn2] = nr;
    lc_pool[nr] = lc_pool[p1] + lc_pool[p2];
    for (int j = 0; j < r; ++j) {
      m1N[k * 15 + j] = m1C[a * 15 + j];
      m2N[k * 15 + j] = m2C[a * 15 + j];
      br1N[k * 15 + j] = br1C[a * 15 + j];
      br2N[k * 15 + j] = br2C[a * 15 + j];
    }
    m1N[k * 15 + r] = i1;
    m2N[k * 15 + r] = i2;
    br1N[k * 15 + r] = b1[k];
    br2N[k * 15 + r] = b2[k];
  }
}

// Fused: Felsenstein step at the new node (phase A, 256 threads) + exact
// ordered log-lik fold and weight update (lane 0). One block per particle.
__global__ __launch_bounds__(256) void k_nfw(
    float* fel_pool, float* st_pool,
    const float* ew, const float* e1K, const float* e2K, const float* sitelog,
    const int* pr1, const int* pr2, const int* ilistN, const int* lc_pool,
    const float* logdf, const float* br1N, const float* br2N,
    const float* logpiC, float* logpiN, const int* idxK, const float* lvp,
    float* logw, float* logws_r, float* loglik, int t, int r) {
  int k = blockIdx.x, tid = threadIdx.x;
  int tn = t - 1;
  int newrow = NN + r * KK + k;
  __shared__ float stbuf[15 * 512];  // 30 KB
  // stage old st rows (pos 0..tn-2) into LDS in logical order
  int nf4 = (tn - 1) * 128;
  for (int q = tid; q < nf4; q += 256) {
    int pos = q >> 7, off = q & 127;
    int row = ilistN[k * 16 + pos];
    ((float4*)stbuf)[q] = *(const float4*)(st_pool + (size_t)row * 512 + off * 4);
  }
  // phase A: new-node Felsenstein + site-term (identical math to round 2)
  int p1 = pr1[k], p2 = pr2[k];
  float e1 = e1K[k], e2 = e2K[k];
  float om1 = __fsub_rn(1.0f, e1), om2 = __fsub_rn(1.0f, e2);
  float ewv[4];
  for (int a = 0; a < 4; ++a) ewv[a] = ew[k * 4 + a];
  for (int s = tid; s < 512; s += 256) {
    float lg[4], ex[4], stat[4];
    for (int a = 0; a < 4; ++a) lg[a] = __fadd_rn(ewv[a], sitelog[s * 4 + a]);
    float m = lg[0];
    for (int a = 1; a < 4; ++a) m = fmaxf(m, lg[a]);
    float ssum = 0.0f;
    for (int a = 0; a < 4; ++a) { ex[a] = expf(__fsub_rn(lg[a], m)); ssum = __fadd_rn(ssum, ex[a]); }
    for (int a = 0; a < 4; ++a) stat[a] = __fdiv_rn(ex[a], ssum);
    float4 f1v = *(const float4*)(fel_pool + (size_t)p1 * 2048 + s * 4);
    float4 f2v = *(const float4*)(fel_pool + (size_t)p2 * 2048 + s * 4);
    float f1a[4] = {f1v.x, f1v.y, f1v.z, f1v.w};
    float f2a[4] = {f2v.x, f2v.y, f2v.z, f2v.w};
    float nf[4];
    for (int a = 0; a < 4; ++a) {
      float q1[4], am = -INFINITY;
      for (int b = 0; b < 4; ++b) {
        float P = __fadd_rn((a == b) ? e1 : 0.0f, __fmul_rn(om1, stat[b]));
        float lp = logf(__fadd_rn(P, 1e-30f));
        q1[b] = __fadd_rn(lp, f1a[b]);
        am = fmaxf(am, q1[b]);
      }
      am = fin_or0(am);
      float se = 0.0f;
      for (int b = 0; b < 4; ++b) se = __fadd_rn(se, expf(__fsub_rn(q1[b], am)));
      float h1 = __fadd_rn(logf(se), am);
      float q2[4], am2 = -INFINITY;
      for (int b = 0; b < 4; ++b) {
        float P = __fadd_rn((a == b) ? e2 : 0.0f, __fmul_rn(om2, stat[b]));
        float lp = logf(__fadd_rn(P, 1e-30f));
        q2[b] = __fadd_rn(lp, f2a[b]);
        am2 = fmaxf(am2, q2[b]);
      }
      am2 = fin_or0(am2);
      float se2 = 0.0f;
      for (int b = 0; b < 4; ++b) se2 = __fadd_rn(se2, expf(__fsub_rn(q2[b], am2)));
      float h2 = __fadd_rn(logf(se2), am2);
      nf[a] = __fadd_rn(h1, h2);
    }
    *(float4*)(fel_pool + (size_t)newrow * 2048 + s * 4) =
        make_float4(nf[0], nf[1], nf[2], nf[3]);
    float q3[4], am3 = -INFINITY;
    for (int a = 0; a < 4; ++a) {
      q3[a] = __fadd_rn(nf[a], logf(stat[a]));
      am3 = fmaxf(am3, q3[a]);
    }
    am3 = fin_or0(am3);
    float se3 = 0.0f;
    for (int a = 0; a < 4; ++a) se3 = __fadd_rn(se3, expf(__fsub_rn(q3[a], am3)));
    float stv = __fadd_rn(logf(se3), am3);
    stbuf[(tn - 1) * 512 + s] = stv;
    st_pool[(size_t)newrow * 512 + s] = stv;
  }
  __syncthreads();
  if (tid == 0) {
    // exact ordered left-fold (bit-identical to reference reduce order)
    float ll = 0.0f;
    const float4* b4 = (const float4*)stbuf;
    int tot = tn * 128;
    for (int q = 0; q < tot; ++q) {
      float4 v = b4[q];
      ll = __fadd_rn(ll, v.x);
      ll = __fadd_rn(ll, v.y);
      ll = __fadd_rn(ll, v.z);
      ll = __fadd_rn(ll, v.w);
    }
    float lt = 0.0f;
    for (int pos = 0; pos < tn; ++pos) {
      int row = ilistN[k * 16 + pos];
      int idx = 2 * lc_pool[row] - 3;
      if (idx < 0) idx = 0;
      lt = __fadd_rn(lt, logdf[idx]);
    }
    lt = -lt;
    float s1 = 0.0f, s2 = 0.0f;
    for (int j = 0; j <= r; ++j) {
      s1 = __fadd_rn(s1, -br1N[k * 15 + j]);
      s2 = __fadd_rn(s2, -br2N[k * 15 + j]);
    }
    float lb = __fadd_rn(s1, s2);
    float lpi = __fadd_rn(__fadd_rn(ll, lt), lb);
    float prev = logpiC[idxK[k]];
    float lw = __fsub_rn(__fadd_rn(__fsub_rn(lpi, prev), 0.0f), lvp[k]);
    logpiN[k] = lpi;
    logw[k] = lw;
    logws_r[k] = lw;
    loglik[k] = ll;
  }
}

// final: parallel. Exact max / first-argmax; parallel exp-sum only hits out[0].
__global__ void k_final(const float* logws, const float* loglik,
                        const int* m1D, const int* m2D,
                        const float* br1D, const float* br2D, float* out) {
  int j = threadIdx.x;  // 128
  out[1 + j] = loglik[j];
  __shared__ float sm[2];
  __shared__ float ssum[2];
  __shared__ int si[2];
  float c = logf(128.0f);
  float z = 0.0f;
  for (int r = 0; r < NR; ++r) {
    float v = __fsub_rn(logws[r * KK + j], c);
    float m = v;
    for (int d = 32; d > 0; d >>= 1) m = fmaxf(m, __shfl_xor(m, d, 64));
    if ((j & 63) == 0) sm[j >> 6] = m;
    __syncthreads();
    float gm = fin_or0(fmaxf(sm[0], sm[1]));
    float e = expf(__fsub_rn(v, gm));
    for (int d = 32; d > 0; d >>= 1) e = __fadd_rn(e, __shfl_xor(e, d, 64));
    if ((j & 63) == 0) ssum[j >> 6] = e;
    __syncthreads();
    if (j == 0) z = __fadd_rn(z, __fadd_rn(logf(__fadd_rn(ssum[0], ssum[1])), gm));
    __syncthreads();
  }
  if (j == 0) out[0] = z;
  float lv = loglik[j];
  float m2 = lv;
  for (int d = 32; d > 0; d >>= 1) m2 = fmaxf(m2, __shfl_xor(m2, d, 64));
  if ((j & 63) == 0) sm[j >> 6] = m2;
  __syncthreads();
  float gm2 = fmaxf(sm[0], sm[1]);
  int cand = (lv == gm2) ? j : 9999;
  for (int d = 32; d > 0; d >>= 1) { int o = __shfl_xor(cand, d, 64); cand = (o < cand) ? o : cand; }
  if ((j & 63) == 0) si[j >> 6] = cand;
  __syncthreads();
  int bi = (si[0] < si[1]) ? si[0] : si[1];
  if (j < NR) {
    out[129 + j] = (float)m1D[bi * 15 + j];
    out[144 + j] = (float)m2D[bi * 15 + j];
    out[159 + j] = br1D[bi * 15 + j];
    out[174 + j] = br2D[bi * 15 + j];
  }
}

// ---------------- host: key schedule + orchestration ----------------
static void split5_host(uint32_t* key0, uint32_t* key1, uint32_t out[8]) {
#if PARTITIONABLE
  uint32_t nk0, nk1, o0, o1;
  tf2x32(*key0, *key1, 0u, 0u, &nk0, &nk1);
  for (int j = 1; j < 5; ++j) {
    tf2x32(*key0, *key1, 0u, (uint32_t)j, &o0, &o1);
    out[2 * (j - 1)] = o0;
    out[2 * (j - 1) + 1] = o1;
  }
  *key0 = nk0; *key1 = nk1;
#else
  uint32_t a0[5], a1[5];
  for (int i = 0; i < 5; ++i) tf2x32(*key0, *key1, (uint32_t)i, (uint32_t)(i + 5), &a0[i], &a1[i]);
  uint32_t flat[10] = {a0[0], a0[1], a0[2], a0[3], a0[4], a1[0], a1[1], a1[2], a1[3], a1[4]};
  *key0 = flat[0]; *key1 = flat[1];
  for (int j = 0; j < 8; ++j) out[j] = flat[2 + j];
#endif
}

extern "C" void kernel_launch(void* const* d_in, const int* in_sizes, int n_in,
                              void* d_out, int out_size, void* d_ws, size_t ws_size,
                              hipStream_t stream) {
  const float* data = (const float*)d_in[0];
  const float* datab = (const float*)d_in[1];
  const float* Wenc = (const float*)d_in[3];
  const float* Wmerge = (const float*)d_in[4];
  const float* Wstat = (const float*)d_in[5];
  const float* Wpos = (const float*)d_in[6];
  const float* Wsite = (const float*)d_in[7];
  float* out = (float*)d_out;

  char* base = (char*)d_ws;
  size_t off = 0;
  auto alloc = [&](size_t bytes) -> void* {
    void* p = base + off;
    off += (bytes + 255) & ~(size_t)255;
    return p;
  };
  float* fel_pool = (float*)alloc((size_t)NROWS * 2048 * 4);
  float* st_pool = (float*)alloc((size_t)NROWS * 512 * 4);
  float* emb_pool = (float*)alloc((size_t)NROWS * 64 * 4);
  int* lc_pool = (int*)alloc((size_t)NROWS * 4);
  int* ilist[2]; int* m1[2]; int* m2[2]; float* br1[2]; float* br2[2]; float* logpi[2];
  for (int b = 0; b < 2; ++b) ilist[b] = (int*)alloc((size_t)KK * 16 * 4);
  for (int b = 0; b < 2; ++b) m1[b] = (int*)alloc((size_t)KK * 15 * 4);
  for (int b = 0; b < 2; ++b) m2[b] = (int*)alloc((size_t)KK * 15 * 4);
  for (int b = 0; b < 2; ++b) br1[b] = (float*)alloc((size_t)KK * 15 * 4);
  for (int b = 0; b < 2; ++b) br2[b] = (float*)alloc((size_t)KK * 15 * 4);
  for (int b = 0; b < 2; ++b) logpi[b] = (float*)alloc((size_t)KK * 4);
  float* logw = (float*)alloc(KK * 4);
  float* logws = (float*)alloc(NR * KK * 4);
  float* loglik = (float*)alloc(KK * 4);
  int* idxK = (int*)alloc(KK * 4);
  int* idx1 = (int*)alloc(KK * 4);
  int* idx2 = (int*)alloc(KK * 4);
  float* b1 = (float*)alloc(KK * 4);
  float* b2 = (float*)alloc(KK * 4);
  float* lvp = (float*)alloc(KK * 4);
  float* ew = (float*)alloc(KK * 4 * 4);
  float* e1K = (float*)alloc(KK * 4);
  float* e2K = (float*)alloc(KK * 4);
  int* pr1 = (int*)alloc(KK * 4);
  int* pr2 = (int*)alloc(KK * 4);
  float* sitelog = (float*)alloc(SS * 4 * 4);
  float* logdf = (float*)alloc(33 * 4);
  float* ew0 = (float*)alloc(NN * 4 * 4);
  (void)ws_size; (void)in_sizes; (void)n_in; (void)out_size;

  // setup
  k_init<<<1, 128, 0, stream>>>(logw, logpi[0], lc_pool, ilist[0], logdf);
  k_sitelog<<<8, 256, 0, stream>>>(Wpos, Wsite, sitelog);
  k_emb0<<<NN, 256, 0, stream>>>(data, Wenc, Wstat, emb_pool, ew0);
  k_leaffel<<<128, 256, 0, stream>>>(datab, fel_pool);
  k_leafterm<<<32, 256, 0, stream>>>(fel_pool, ew0, sitelog, st_pool);

  uint32_t key0 = 0u, key1 = 42u;  // jax.random.key(42)
  for (int r = 0; r < NR; ++r) {
    uint32_t ks[8];
    split5_host(&key0, &key1, ks);  // key, k1, k2, k3, k4
    int t = NN - r;
    int cur = r & 1, nxt = cur ^ 1;
    k_resample_prop<<<KK + 1, 128, 0, stream>>>(ks[0], ks[1], ks[2], ks[3], ks[4],
                                                ks[5], ks[6], ks[7], t, logw, idxK,
                                                idx1, idx2, b1, b2, lvp);
    k_newemb_bk<<<KK + 1, 64, 0, stream>>>(emb_pool, Wmerge, Wstat,
                                           ilist[cur], ilist[nxt], idxK, idx1, idx2,
                                           b1, b2, m1[cur], m1[nxt], m2[cur], m2[nxt],
                                           br1[cur], br1[nxt], br2[cur], br2[nxt],
                                           lc_pool, pr1, pr2, ew, e1K, e2K, t, r);
    k_nfw<<<KK, 256, 0, stream>>>(fel_pool, st_pool, ew, e1K, e2K, sitelog,
                                  pr1, pr2, ilist[nxt], lc_pool, logdf,
                                  br1[nxt], br2[nxt], logpi[cur], logpi[nxt],
                                  idxK, lvp, logw, logws + r * KK, loglik, t, r);
  }
  // after r=14: nxt == 1
  k_final<<<1, 128, 0, stream>>>(logws, loglik, m1[1], m2[1], br1[1], br2[1], out);
}

// Round 4
// 577.516 us; speedup vs baseline: 3.4294x; 1.1269x over previous
//
#include <hip/hip_runtime.h>
#include <stdint.h>

// VCSMC: N=16 taxa, K=128 particles, S=512 sites, A=4, D=64, 15 rounds.
// Bit-exact threefry (partitionable) + order-faithful float32 so all argmax
// decisions match the JAX reference. Round 4: one fused kernel per round
// (particle == block; only __syncthreads needed), 20 total dispatches.
// k_emb0 rewritten as per-lane column chain (no LDS staging). All
// decision-feeding arithmetic is bit-identical to the passing round-3.

#define NN 16
#define KK 128
#define SS 512
#define NR 15
#define PARTITIONABLE 1
#define TINYF 1.17549435e-38f
#define NROWS (NN + NR * KK)   // 1936 pool rows

// ---------------- threefry2x32 (JAX-exact) ----------------
__host__ __device__ __forceinline__ void tf2x32(uint32_t k0, uint32_t k1,
                                                uint32_t c0, uint32_t c1,
                                                uint32_t* o0, uint32_t* o1) {
  uint32_t ks2 = k0 ^ k1 ^ 0x1BD11BDAu;
  uint32_t x0 = c0 + k0, x1 = c1 + k1;
  uint32_t ks[3] = {k0, k1, ks2};
  const uint32_t RA[4] = {13u, 15u, 26u, 6u};
  const uint32_t RB[4] = {17u, 29u, 16u, 24u};
#pragma unroll
  for (int i = 0; i < 5; ++i) {
#pragma unroll
    for (int j = 0; j < 4; ++j) {
      uint32_t r = (i & 1) ? RB[j] : RA[j];
      x0 += x1;
      x1 = (x1 << r) | (x1 >> (32u - r));
      x1 ^= x0;
    }
    x0 += ks[(i + 1) % 3];
    x1 += ks[(i + 2) % 3] + (uint32_t)(i + 1);
  }
  *o0 = x0; *o1 = x1;
}

__device__ __forceinline__ uint32_t rbits32(uint32_t ka, uint32_t kb,
                                            uint32_t i, uint32_t total) {
#if PARTITIONABLE
  uint32_t o0, o1;
  tf2x32(ka, kb, 0u, i, &o0, &o1);
  return o0 ^ o1;
#else
  uint32_t half = total >> 1;
  uint32_t o0, o1;
  if (i < half) { tf2x32(ka, kb, i, i + half, &o0, &o1); return o0; }
  tf2x32(ka, kb, i - half, i, &o0, &o1);
  return o1;
#endif
}

__device__ __forceinline__ float bits_unif(uint32_t b) {
  return __uint_as_float((b >> 9) | 0x3f800000u) - 1.0f;  // [0,1)
}

// XLA CPU fast-tanh (with_fma=false) replicated.
__device__ __forceinline__ float xla_tanh(float x) {
  float ax = fabsf(x);
  float xc = fminf(fmaxf(x, -7.90531110763549805f), 7.90531110763549805f);
  float x2 = __fmul_rn(xc, xc);
  float num = -2.76076847742355e-16f;
  num = __fadd_rn(__fmul_rn(x2, num), 2.00018790482477e-13f);
  num = __fadd_rn(__fmul_rn(x2, num), -8.60467152213735e-11f);
  num = __fadd_rn(__fmul_rn(x2, num), 5.12229709037114e-08f);
  num = __fadd_rn(__fmul_rn(x2, num), 1.48572235717979e-05f);
  num = __fadd_rn(__fmul_rn(x2, num), 6.37261928875436e-04f);
  num = __fadd_rn(__fmul_rn(x2, num), 4.89352455891786e-03f);
  num = __fmul_rn(xc, num);
  float den = 1.19825839466702e-06f;
  den = __fadd_rn(__fmul_rn(x2, den), 1.18534705686654e-04f);
  den = __fadd_rn(__fmul_rn(x2, den), 2.26843463243900e-03f);
  den = __fadd_rn(__fmul_rn(x2, den), 4.89352518554385e-03f);
  float r = __fdiv_rn(num, den);
  return (ax < 0.0004f) ? x : r;
}

__device__ __forceinline__ float fin_or0(float v) {
  return (v > -INFINITY && v < INFINITY) ? v : 0.0f;
}

// ---------------- setup ----------------
// blocks 0..63: leaf fel rows; 64..71: site logits; 72: misc init
__global__ void k_setup(const float* datab, const float* Wpos, const float* Wsite,
                        float* fel_pool, float* sitelog, float* logw0,
                        float* logpi0, int* lc_pool, int* ilist0, float* logdf) {
  int b = blockIdx.x, tid = threadIdx.x;
  if (b < 64) {
    int id = b * 256 + tid;
    fel_pool[id] = logf(datab[id]);
    fel_pool[16384 + id] = logf(datab[16384 + id]);
  } else if (b < 72) {
    int id = (b - 64) * 256 + tid;  // 2048
    int s = id >> 2, aa = id & 3;
    float acc = 0.0f;
    for (int c = 0; c < 16; ++c) acc = fmaf(Wpos[s * 16 + c], Wsite[c * 4 + aa], acc);
    sitelog[id] = acc;
  } else {
    if (tid < KK) {
      logw0[tid] = 0.0f;
      logpi0[tid] = 0.0f;
      for (int nn2 = 0; nn2 < NN; ++nn2) ilist0[tid * 16 + nn2] = nn2;
    }
    if (tid < NN) lc_pool[tid] = 1;
    if (tid == 0) {
      double vv[33];
      vv[0] = 0.0; vv[1] = 0.0;
      for (int i = 2; i <= 32; ++i) vv[i] = vv[i - 2] + log((double)i);
      for (int i = 0; i < 33; ++i) logdf[i] = (float)vv[i];
    }
  }
}

// seq_encoder: lane d computes emb(n,d) with the exact sequential fmaf chain;
// Wenc loads are wave-coalesced, data loads wave-uniform; unroll batches loads.
__global__ __launch_bounds__(64) void k_emb0(const float* data, const float* Wenc,
                                             const float* Wstat, float* emb_pool,
                                             float* ew0) {
  int n = blockIdx.x, d = threadIdx.x;
  __shared__ float ne[64];
  const float* dp = data + n * 2048;
  const float* wp = Wenc + d;
  float acc = 0.0f;
#pragma unroll 32
  for (int i = 0; i < 2048; ++i) acc = fmaf(dp[i], wp[(size_t)i * 64], acc);
  float v = xla_tanh(acc);
  ne[d] = v;
  emb_pool[n * 64 + d] = v;
  __syncthreads();
  if (d < 4) {
    float s = 0.0f;
    for (int c = 0; c < 64; ++c) s = fmaf(ne[c], Wstat[c * 4 + d], s);
    ew0[n * 4 + d] = s;
  }
}

__global__ void k_leafterm(const float* fel_pool, const float* ew0,
                           const float* sitelog, float* st_pool) {
  int id = blockIdx.x * blockDim.x + threadIdx.x;
  if (id >= NN * SS) return;
  int n = id >> 9, s = id & 511;
  float lg[4], ex[4], stat[4];
  for (int a = 0; a < 4; ++a) lg[a] = __fadd_rn(ew0[n * 4 + a], sitelog[s * 4 + a]);
  float m = lg[0];
  for (int a = 1; a < 4; ++a) m = fmaxf(m, lg[a]);
  float ssum = 0.0f;
  for (int a = 0; a < 4; ++a) { ex[a] = expf(__fsub_rn(lg[a], m)); ssum = __fadd_rn(ssum, ex[a]); }
  for (int a = 0; a < 4; ++a) stat[a] = __fdiv_rn(ex[a], ssum);
  float q[4], am = -INFINITY;
  for (int a = 0; a < 4; ++a) {
    q[a] = __fadd_rn(fel_pool[n * 2048 + s * 4 + a], logf(stat[a]));
    am = fmaxf(am, q[a]);
  }
  am = fin_or0(am);
  float se = 0.0f;
  for (int a = 0; a < 4; ++a) se = __fadd_rn(se, expf(__fsub_rn(q[a], am)));
  st_pool[n * 512 + s] = __fadd_rn(logf(se), am);
}

// ---------------- the fused per-round kernel ----------------
// One block per particle k. Phases separated by __syncthreads only:
//  1. resample draw k (tids 0..127) + proposal (tid 128)
//  2. cat-load / index-list+history bookkeeping / exp(-b)
//  3. newemb chain (tids 0..63) | stage old st rows to LDS (tids 64..255)
//  4. ew = ne @ Wstat (tids 0..3)
//  5. new-node Felsenstein + site-term (all 256 over 512 sites)
//  6. exact ordered log-lik fold + weight update (tid 0)
__global__ __launch_bounds__(256) void k_round(
    uint32_t ka, uint32_t kb, uint32_t k2a, uint32_t k2b,
    uint32_t k3a, uint32_t k3b, uint32_t k4a, uint32_t k4b,
    int t, int r,
    const float* logwC, float* logwN,
    const float* logpiC, float* logpiN,
    const int* ilistC, int* ilistN,
    const int* m1C, int* m1N, const int* m2C, int* m2N,
    const float* br1C, float* br1N, const float* br2C, float* br2N,
    float* emb_pool, float* fel_pool, float* st_pool, int* lc_pool,
    const float* Wmerge, const float* Wstat, const float* sitelog,
    const float* logdf, float* logws_r, float* loglik) {
  int k = blockIdx.x, tid = threadIdx.x;
  int tn = t - 1, tn2 = t - 2;
  int newrow = NN + r * KK + k;
  __shared__ float stbuf[15 * 512];  // 30 KB
  __shared__ float cat[128];
  __shared__ float ne[64];
  __shared__ float ewl[4];
  __shared__ float smax[4];
  __shared__ int sidx[4];
  __shared__ int sA, sI1, sI2;
  __shared__ float sB1, sB2, sLvp, sE1, sE2;
  __shared__ int ilN[16];
  __shared__ int lcb[16];
  __shared__ float brb1[15], brb2[15];

  // ---- phase 1: resample (gumbel argmax, exact) + proposal ----
  float v = -INFINITY;
  if (tid < 128) {
    uint32_t bits = rbits32(ka, kb, (uint32_t)(k * KK + tid), KK * KK);
    float f = bits_unif(bits);
    float u = fmaxf(TINYF, __fadd_rn(f, TINYF));
    float gv = -logf(-logf(u));
    v = __fadd_rn(gv, logwC[tid]);
  } else if (tid == 128) {
    uint32_t h = rbits32(k2a, k2b, (uint32_t)k, 256u);
    uint32_t l = rbits32(k2a, k2b, (uint32_t)(128 + k), 256u);
    uint32_t span = (uint32_t)(t * (t - 1) / 2);
    uint32_t mult = 65536u % span;
    mult = (mult * mult) % span;
    uint32_t off = ((h % span) * mult + (l % span)) % span;
    int p = (int)off;
    int a1 = 0, rem = p, rl = t - 1;
    while (rem >= rl) { rem -= rl; ++a1; --rl; }
    sI1 = a1;
    sI2 = a1 + 1 + rem;
    uint32_t bb = rbits32(k3a, k3b, (uint32_t)k, 128u);
    float e1 = -log1pf(-bits_unif(bb));
    bb = rbits32(k4a, k4b, (uint32_t)k, 128u);
    float e2 = -log1pf(-bits_unif(bb));
    sB1 = e1; sB2 = e2;
    float lnp = logf((float)span);
    sLvp = __fadd_rn(__fadd_rn(-lnp, -e1), -e2);
  }
  float m = v;
  for (int d = 32; d > 0; d >>= 1) m = fmaxf(m, __shfl_xor(m, d, 64));
  int w = tid >> 6;
  if ((tid & 63) == 0) smax[w] = m;
  __syncthreads();
  float gm = fmaxf(fmaxf(smax[0], smax[1]), fmaxf(smax[2], smax[3]));
  int cand = (v == gm) ? tid : 9999;
  for (int d = 32; d > 0; d >>= 1) {
    int o = __shfl_xor(cand, d, 64);
    cand = (o < cand) ? o : cand;
  }
  if ((tid & 63) == 0) sidx[w] = cand;
  __syncthreads();
  if (tid == 0) {
    int b0 = (sidx[0] < sidx[1]) ? sidx[0] : sidx[1];
    int b1_ = (sidx[2] < sidx[3]) ? sidx[2] : sidx[3];
    sA = (b0 < b1_) ? b0 : b1_;
  }
  __syncthreads();
  int a = sA, i1 = sI1, i2 = sI2;
  int p1 = ilistC[a * 16 + i1];
  int p2 = ilistC[a * 16 + i2];

  // ---- phase 2: cat load | bookkeeping | exp(-b) ----
  if (tid < 64) {
    cat[tid] = emb_pool[p1 * 64 + tid];
    cat[64 + tid] = emb_pool[p2 * 64 + tid];
  } else if (tid >= 64 && tid < 80) {
    int pos = tid - 64;
    if (pos < tn2) {
      int src = pos + (pos >= i1) + (pos >= (i2 - 1));
      int row = ilistC[a * 16 + src];
      ilN[pos] = row;
      ilistN[k * 16 + pos] = row;
      lcb[pos] = lc_pool[row];
    } else if (pos == tn2) {
      ilN[pos] = newrow;
      ilistN[k * 16 + pos] = newrow;
      int lcnew = lc_pool[p1] + lc_pool[p2];
      lcb[pos] = lcnew;
      lc_pool[newrow] = lcnew;
    }
  } else if (tid >= 96 && tid < 96 + NR) {
    int j = tid - 96;
    if (j < r) {
      int v1 = m1C[a * 15 + j]; m1N[k * 15 + j] = v1;
      int v2 = m2C[a * 15 + j]; m2N[k * 15 + j] = v2;
      float w1 = br1C[a * 15 + j]; br1N[k * 15 + j] = w1; brb1[j] = w1;
      float w2 = br2C[a * 15 + j]; br2N[k * 15 + j] = w2; brb2[j] = w2;
    } else if (j == r) {
      m1N[k * 15 + r] = i1;
      m2N[k * 15 + r] = i2;
      br1N[k * 15 + r] = sB1;
      br2N[k * 15 + r] = sB2;
      brb1[r] = sB1;
      brb2[r] = sB2;
    }
  } else if (tid == 128) {
    sE1 = expf(-sB1);
  } else if (tid == 129) {
    sE2 = expf(-sB2);
  }
  __syncthreads();

  // ---- phase 3: newemb chain | stage old st rows ----
  if (tid < 64) {
    float acc = 0.0f;
    for (int c = 0; c < 128; ++c) acc = fmaf(cat[c], Wmerge[c * 64 + tid], acc);
    float vv = xla_tanh(acc);
    ne[tid] = vv;
    emb_pool[newrow * 64 + tid] = vv;
  } else {
    int nf4 = tn2 * 128;
    int base = tid - 64;  // 192 threads
    float4 tmp[10];
#pragma unroll
    for (int it = 0; it < 10; ++it) {
      int q = base + it * 192;
      if (q < nf4)
        tmp[it] = *(const float4*)(st_pool + (size_t)ilN[q >> 7] * 512 + ((q & 127) << 2));
    }
#pragma unroll
    for (int it = 0; it < 10; ++it) {
      int q = base + it * 192;
      if (q < nf4) ((float4*)stbuf)[q] = tmp[it];
    }
  }
  __syncthreads();

  // ---- phase 4: ew ----
  if (tid < 4) {
    float s = 0.0f;
    for (int c = 0; c < 64; ++c) s = fmaf(ne[c], Wstat[c * 4 + tid], s);
    ewl[tid] = s;
  }
  __syncthreads();

  // ---- phase 5: new-node Felsenstein + site-term ----
  {
    float e1 = sE1, e2 = sE2;
    float om1 = __fsub_rn(1.0f, e1), om2 = __fsub_rn(1.0f, e2);
    float ewv[4];
    for (int aa = 0; aa < 4; ++aa) ewv[aa] = ewl[aa];
    for (int s = tid; s < 512; s += 256) {
      float lg[4], ex[4], stat[4];
      for (int aa = 0; aa < 4; ++aa) lg[aa] = __fadd_rn(ewv[aa], sitelog[s * 4 + aa]);
      float mm = lg[0];
      for (int aa = 1; aa < 4; ++aa) mm = fmaxf(mm, lg[aa]);
      float ssum = 0.0f;
      for (int aa = 0; aa < 4; ++aa) { ex[aa] = expf(__fsub_rn(lg[aa], mm)); ssum = __fadd_rn(ssum, ex[aa]); }
      for (int aa = 0; aa < 4; ++aa) stat[aa] = __fdiv_rn(ex[aa], ssum);
      float4 f1v = *(const float4*)(fel_pool + (size_t)p1 * 2048 + s * 4);
      float4 f2v = *(const float4*)(fel_pool + (size_t)p2 * 2048 + s * 4);
      float f1a[4] = {f1v.x, f1v.y, f1v.z, f1v.w};
      float f2a[4] = {f2v.x, f2v.y, f2v.z, f2v.w};
      float nf[4];
      for (int aa = 0; aa < 4; ++aa) {
        float q1[4], am = -INFINITY;
        for (int bb = 0; bb < 4; ++bb) {
          float P = __fadd_rn((aa == bb) ? e1 : 0.0f, __fmul_rn(om1, stat[bb]));
          float lp = logf(__fadd_rn(P, 1e-30f));
          q1[bb] = __fadd_rn(lp, f1a[bb]);
          am = fmaxf(am, q1[bb]);
        }
        am = fin_or0(am);
        float se = 0.0f;
        for (int bb = 0; bb < 4; ++bb) se = __fadd_rn(se, expf(__fsub_rn(q1[bb], am)));
        float h1 = __fadd_rn(logf(se), am);
        float q2[4], am2 = -INFINITY;
        for (int bb = 0; bb < 4; ++bb) {
          float P = __fadd_rn((aa == bb) ? e2 : 0.0f, __fmul_rn(om2, stat[bb]));
          float lp = logf(__fadd_rn(P, 1e-30f));
          q2[bb] = __fadd_rn(lp, f2a[bb]);
          am2 = fmaxf(am2, q2[bb]);
        }
        am2 = fin_or0(am2);
        float se2 = 0.0f;
        for (int bb = 0; bb < 4; ++bb) se2 = __fadd_rn(se2, expf(__fsub_rn(q2[bb], am2)));
        float h2 = __fadd_rn(logf(se2), am2);
        nf[aa] = __fadd_rn(h1, h2);
      }
      *(float4*)(fel_pool + (size_t)newrow * 2048 + s * 4) =
          make_float4(nf[0], nf[1], nf[2], nf[3]);
      float q3[4], am3 = -INFINITY;
      for (int aa = 0; aa < 4; ++aa) {
        q3[aa] = __fadd_rn(nf[aa], logf(stat[aa]));
        am3 = fmaxf(am3, q3[aa]);
      }
      am3 = fin_or0(am3);
      float se3 = 0.0f;
      for (int aa = 0; aa < 4; ++aa) se3 = __fadd_rn(se3, expf(__fsub_rn(q3[aa], am3)));
      float stv = __fadd_rn(logf(se3), am3);
      stbuf[tn2 * 512 + s] = stv;
      st_pool[(size_t)newrow * 512 + s] = stv;
    }
  }
  __syncthreads();

  // ---- phase 6: exact ordered fold + weights (tid 0) ----
  if (tid == 0) {
    const float4* b4 = (const float4*)stbuf;
    int tot4 = tn * 128;  // multiple of 8
    float ll = 0.0f;
    float4 pre[8];
#pragma unroll
    for (int i = 0; i < 8; ++i) pre[i] = b4[i];
    for (int q = 8; q <= tot4; q += 8) {
      float4 cur[8];
#pragma unroll
      for (int i = 0; i < 8; ++i) cur[i] = pre[i];
      if (q < tot4) {
#pragma unroll
        for (int i = 0; i < 8; ++i) pre[i] = b4[q + i];
      }
#pragma unroll
      for (int i = 0; i < 8; ++i) {
        ll = __fadd_rn(ll, cur[i].x);
        ll = __fadd_rn(ll, cur[i].y);
        ll = __fadd_rn(ll, cur[i].z);
        ll = __fadd_rn(ll, cur[i].w);
      }
    }
    float lt = 0.0f;
    for (int pos = 0; pos < tn; ++pos) {
      int idx = 2 * lcb[pos] - 3;
      if (idx < 0) idx = 0;
      lt = __fadd_rn(lt, logdf[idx]);
    }
    lt = -lt;
    float s1 = 0.0f, s2 = 0.0f;
    for (int j = 0; j <= r; ++j) {
      s1 = __fadd_rn(s1, -brb1[j]);
      s2 = __fadd_rn(s2, -brb2[j]);
    }
    float lb = __fadd_rn(s1, s2);
    float lpi = __fadd_rn(__fadd_rn(ll, lt), lb);
    float prev = logpiC[a];
    float lw = __fsub_rn(__fadd_rn(__fsub_rn(lpi, prev), 0.0f), sLvp);
    logpiN[k] = lpi;
    logwN[k] = lw;
    logws_r[k] = lw;
    loglik[k] = ll;
  }
}

// final: parallel. Exact max / first-argmax; parallel exp-sum only hits out[0].
__global__ void k_final(const float* logws, const float* loglik,
                        const int* m1D, const int* m2D,
                        const float* br1D, const float* br2D, float* out) {
  int j = threadIdx.x;  // 128
  out[1 + j] = loglik[j];
  __shared__ float sm[2];
  __shared__ float ssum[2];
  __shared__ int si[2];
  float c = logf(128.0f);
  float z = 0.0f;
  for (int r = 0; r < NR; ++r) {
    float v = __fsub_rn(logws[r * KK + j], c);
    float m = v;
    for (int d = 32; d > 0; d >>= 1) m = fmaxf(m, __shfl_xor(m, d, 64));
    if ((j & 63) == 0) sm[j >> 6] = m;
    __syncthreads();
    float gm = fin_or0(fmaxf(sm[0], sm[1]));
    float e = expf(__fsub_rn(v, gm));
    for (int d = 32; d > 0; d >>= 1) e = __fadd_rn(e, __shfl_xor(e, d, 64));
    if ((j & 63) == 0) ssum[j >> 6] = e;
    __syncthreads();
    if (j == 0) z = __fadd_rn(z, __fadd_rn(logf(__fadd_rn(ssum[0], ssum[1])), gm));
    __syncthreads();
  }
  if (j == 0) out[0] = z;
  float lv = loglik[j];
  float m2 = lv;
  for (int d = 32; d > 0; d >>= 1) m2 = fmaxf(m2, __shfl_xor(m2, d, 64));
  if ((j & 63) == 0) sm[j >> 6] = m2;
  __syncthreads();
  float gm2 = fmaxf(sm[0], sm[1]);
  int cand = (lv == gm2) ? j : 9999;
  for (int d = 32; d > 0; d >>= 1) {
    int o = __shfl_xor(cand, d, 64);
    cand = (o < cand) ? o : cand;
  }
  if ((j & 63) == 0) si[j >> 6] = cand;
  __syncthreads();
  int bi = (si[0] < si[1]) ? si[0] : si[1];
  if (j < NR) {
    out[129 + j] = (float)m1D[bi * 15 + j];
    out[144 + j] = (float)m2D[bi * 15 + j];
    out[159 + j] = br1D[bi * 15 + j];
    out[174 + j] = br2D[bi * 15 + j];
  }
}

// ---------------- host: key schedule + orchestration ----------------
static void split5_host(uint32_t* key0, uint32_t* key1, uint32_t out[8]) {
#if PARTITIONABLE
  uint32_t nk0, nk1, o0, o1;
  tf2x32(*key0, *key1, 0u, 0u, &nk0, &nk1);
  for (int j = 1; j < 5; ++j) {
    tf2x32(*key0, *key1, 0u, (uint32_t)j, &o0, &o1);
    out[2 * (j - 1)] = o0;
    out[2 * (j - 1) + 1] = o1;
  }
  *key0 = nk0; *key1 = nk1;
#else
  uint32_t a0[5], a1[5];
  for (int i = 0; i < 5; ++i) tf2x32(*key0, *key1, (uint32_t)i, (uint32_t)(i + 5), &a0[i], &a1[i]);
  uint32_t flat[10] = {a0[0], a0[1], a0[2], a0[3], a0[4], a1[0], a1[1], a1[2], a1[3], a1[4]};
  *key0 = flat[0]; *key1 = flat[1];
  for (int j = 0; j < 8; ++j) out[j] = flat[2 + j];
#endif
}

extern "C" void kernel_launch(void* const* d_in, const int* in_sizes, int n_in,
                              void* d_out, int out_size, void* d_ws, size_t ws_size,
                              hipStream_t stream) {
  const float* data = (const float*)d_in[0];
  const float* datab = (const float*)d_in[1];
  const float* Wenc = (const float*)d_in[3];
  const float* Wmerge = (const float*)d_in[4];
  const float* Wstat = (const float*)d_in[5];
  const float* Wpos = (const float*)d_in[6];
  const float* Wsite = (const float*)d_in[7];
  float* out = (float*)d_out;

  char* base = (char*)d_ws;
  size_t off = 0;
  auto alloc = [&](size_t bytes) -> void* {
    void* p = base + off;
    off += (bytes + 255) & ~(size_t)255;
    return p;
  };
  float* fel_pool = (float*)alloc((size_t)NROWS * 2048 * 4);
  float* st_pool = (float*)alloc((size_t)NROWS * 512 * 4);
  float* emb_pool = (float*)alloc((size_t)NROWS * 64 * 4);
  int* lc_pool = (int*)alloc((size_t)NROWS * 4);
  int* ilist[2]; int* m1[2]; int* m2[2]; float* br1[2]; float* br2[2];
  float* logpi[2]; float* logw2[2];
  for (int b = 0; b < 2; ++b) ilist[b] = (int*)alloc((size_t)KK * 16 * 4);
  for (int b = 0; b < 2; ++b) m1[b] = (int*)alloc((size_t)KK * 15 * 4);
  for (int b = 0; b < 2; ++b) m2[b] = (int*)alloc((size_t)KK * 15 * 4);
  for (int b = 0; b < 2; ++b) br1[b] = (float*)alloc((size_t)KK * 15 * 4);
  for (int b = 0; b < 2; ++b) br2[b] = (float*)alloc((size_t)KK * 15 * 4);
  for (int b = 0; b < 2; ++b) logpi[b] = (float*)alloc((size_t)KK * 4);
  for (int b = 0; b < 2; ++b) logw2[b] = (float*)alloc((size_t)KK * 4);
  float* logws = (float*)alloc(NR * KK * 4);
  float* loglik = (float*)alloc(KK * 4);
  float* sitelog = (float*)alloc(SS * 4 * 4);
  float* logdf = (float*)alloc(33 * 4);
  float* ew0 = (float*)alloc(NN * 4 * 4);
  (void)ws_size; (void)in_sizes; (void)n_in; (void)out_size;

  // setup (3 launches)
  k_setup<<<73, 256, 0, stream>>>(datab, Wpos, Wsite, fel_pool, sitelog,
                                  logw2[0], logpi[0], lc_pool, ilist[0], logdf);
  k_emb0<<<NN, 64, 0, stream>>>(data, Wenc, Wstat, emb_pool, ew0);
  k_leafterm<<<32, 256, 0, stream>>>(fel_pool, ew0, sitelog, st_pool);

  uint32_t key0 = 0u, key1 = 42u;  // jax.random.key(42)
  for (int r = 0; r < NR; ++r) {
    uint32_t ks[8];
    split5_host(&key0, &key1, ks);  // key, k1, k2, k3, k4
    int t = NN - r;
    int cur = r & 1, nxt = cur ^ 1;
    k_round<<<KK, 256, 0, stream>>>(
        ks[0], ks[1], ks[2], ks[3], ks[4], ks[5], ks[6], ks[7], t, r,
        logw2[cur], logw2[nxt], logpi[cur], logpi[nxt],
        ilist[cur], ilist[nxt], m1[cur], m1[nxt], m2[cur], m2[nxt],
        br1[cur], br1[nxt], br2[cur], br2[nxt],
        emb_pool, fel_pool, st_pool, lc_pool,
        Wmerge, Wstat, sitelog, logdf, logws + r * KK, loglik);
  }
  // after r=14: nxt == 1
  k_final<<<1, 128, 0, stream>>>(logws, loglik, m1[1], m2[1], br1[1], br2[1], out);
}